// Round 1
// baseline (655.986 us; speedup 1.0000x reference)
//
#include <hip/hip_runtime.h>

// GTEAST layer, round 4: kill the Elds LDS round-trip.
// N_SRC=100000, N_DST=50000, DEG=16, NODE_IN=128, EDGE_IN=64, HID=64, E=800000
// Fold: a = leaky_relu(ef @ (Wa@wa) + ba.wa)  (fp32, exact)
// GEMMs: bf16 v_mfma_f32_16x16x32_bf16, fp32 accum.
//   A-frag: lane q*16+t holds A[m=t][k=q*8+j]
//   B-frag: lane q*16+t holds B^T[n=t][k=q*8+j]  (from W^T rows in LDS)
//   C/D:    lane q*16+t holds C[row=q*4+reg][col=t]
// e-GEMM is computed OPERAND-SWAPPED: MFMA(WeT_frag, ef_frag) -> C[h][edge],
// so edge sits on the t index and e_out stays in registers as a valid m-GEMM
// A-frag under a k-row permutation of Wo (applied once at WoT staging):
//   k' = 128 + (h&32) + ((h>>2)&3)*8 + ((h>>4)&1)*4 + (h&3)   (bijective)
// This removes Elds (LDS 44544->35328 => 4 blocks/CU, 16 waves) and both
// per-iteration lgkmcnt(0) drains + 16 bank-conflicted ds_write_b16.
// One wave = 8 consecutive dsts (128 consecutive edges): src_idx batched via
// 2 coalesced ints/lane + per-iter shuffle; ef prefetched 1 iter ahead; nf
// gather issued before m-GEMM. h_neigh staged fp32 in d_out; K2 in place.

#define ND 50000

typedef __bf16 bf16x8 __attribute__((ext_vector_type(8)));
typedef float f32x4 __attribute__((ext_vector_type(4)));

// fp32 -> bf16 RNE (weights, one-time)
__device__ __forceinline__ unsigned short f2bf(float x) {
  unsigned u = __float_as_uint(x);
  u += 0x7fffu + ((u >> 16) & 1u);
  return (unsigned short)(u >> 16);
}

union Frag8 { bf16x8 v; unsigned u32[4]; };

// 8 floats -> bf16x8, round-half-up (+0x8000) + v_perm pack: ~1.5 VALU/elem
__device__ __forceinline__ bf16x8 pack8(const float* fr) {
  Frag8 f;
  #pragma unroll
  for (int j = 0; j < 4; ++j) {
    unsigned lo = __float_as_uint(fr[2 * j]) + 0x8000u;
    unsigned hi = __float_as_uint(fr[2 * j + 1]) + 0x8000u;
    f.u32[j] = __builtin_amdgcn_perm(hi, lo, 0x07060302);
  }
  return f.v;
}

#define MFMA(a, b, c) __builtin_amdgcn_mfma_f32_16x16x32_bf16((a), (b), (c), 0, 0, 0)

// ---------- K0: v = Wa@wa, c = ba.wa (256 threads, LDS reduce) ----------
extern "C" __global__ void gteast_prep(const float* __restrict__ Wa,
                                       const float* __restrict__ ba,
                                       const float* __restrict__ wa,
                                       float* __restrict__ vc) {
  __shared__ float red[260];
  const int tid = threadIdx.x, k = tid >> 2, p = tid & 3;
  float s = 0.f;
  for (int h = 16 * p; h < 16 * p + 16; ++h) s += Wa[k * 64 + h] * wa[h];
  red[tid] = s;
  if (tid < 4) {
    float sc = 0.f;
    for (int h = 16 * tid; h < 16 * tid + 16; ++h) sc += ba[h] * wa[h];
    red[256 + tid] = sc;
  }
  __syncthreads();
  if (p == 0) vc[k] = red[4 * k] + red[4 * k + 1] + red[4 * k + 2] + red[4 * k + 3];
  if (tid == 0) vc[64] = red[256] + red[257] + red[258] + red[259];
}

// ---------- K1: fused e_out + attention + m + sparsemax + h_neigh ----------
extern "C" __global__ void __launch_bounds__(256, 4)
gteast_edge(const float* __restrict__ nf, const float* __restrict__ ef,
            const int* __restrict__ src_idx,
            const float* __restrict__ We, const float* __restrict__ be,
            const float* __restrict__ Wo, const float* __restrict__ bo,
            const float* __restrict__ vc,
            float* __restrict__ hn_out) {
  __shared__ unsigned short WeT[64 * 72];   // We^T[n][k], stride 72 (16B rows)
  __shared__ unsigned short WoT[64 * 200];  // Wo^T[n][k'], k>=128 rows permuted
  __shared__ float vls[68];                 // v[64], c at [64]

  const int tid = threadIdx.x;
  for (int i = tid; i < 64 * 64; i += 256) {
    int k = i >> 6, n = i & 63;
    WeT[n * 72 + k] = f2bf(We[i]);
  }
  for (int i = tid; i < 192 * 64; i += 256) {
    int k = i >> 6, n = i & 63;
    int kk = k;
    if (k >= 128) {  // permute e_out k-rows to match register A-frag layout
      int h = k - 128;
      kk = 128 + (h & 32) + ((h >> 2) & 3) * 8 + ((h >> 4) & 1) * 4 + (h & 3);
    }
    WoT[n * 200 + kk] = f2bf(Wo[i]);
  }
  if (tid < 65) vls[tid] = vc[tid];
  __syncthreads();

  const int lane = tid & 63, w = tid >> 6;
  const int q = lane >> 4, t = lane & 15;
  const int wid = blockIdx.x * 4 + w;  // 0..6251; 6250 active
  if (wid * 8 >= ND) return;           // after the only __syncthreads

  const float cval = vls[64];
  float boL[4];
  float4 beQ[4];  // be[nt*16 + 4q + r] for the swapped e-GEMM epilogue
  #pragma unroll
  for (int nt = 0; nt < 4; ++nt) {
    boL[nt] = bo[nt * 16 + t];
    beQ[nt] = *reinterpret_cast<const float4*>(be + nt * 16 + 4 * q);
  }
  // logit vector slices (per-quad broadcast reads from LDS)
  float vsl[16];
  #pragma unroll
  for (int j = 0; j < 8; ++j) { vsl[j] = vls[q * 8 + j]; vsl[8 + j] = vls[32 + q * 8 + j]; }

  // batched src_idx: wave's 128 edges, 2 coalesced ints/lane
  const int si0 = src_idx[wid * 128 + lane];
  const int si1 = src_idx[wid * 128 + 64 + lane];

  const long ebase = (long)(wid * 128);

  // --- prologue: prefetch ef(it=0) and nf(it=0) ---
  float4 efn[4];
  {
    const float* er = ef + (ebase + t) * 64 + q * 8;
    efn[0] = *reinterpret_cast<const float4*>(er);
    efn[1] = *reinterpret_cast<const float4*>(er + 4);
    efn[2] = *reinterpret_cast<const float4*>(er + 32);
    efn[3] = *reinterpret_cast<const float4*>(er + 36);
  }
  float hraw[32];
  {
    const int s0 = __shfl(si0, t);
    const float* hp = nf + (long)s0 * 128 + q * 8;
    #pragma unroll
    for (int kc = 0; kc < 4; ++kc) {
      float4 a0 = *reinterpret_cast<const float4*>(hp + kc * 32);
      float4 a1 = *reinterpret_cast<const float4*>(hp + kc * 32 + 4);
      hraw[kc * 8 + 0] = a0.x; hraw[kc * 8 + 1] = a0.y; hraw[kc * 8 + 2] = a0.z; hraw[kc * 8 + 3] = a0.w;
      hraw[kc * 8 + 4] = a1.x; hraw[kc * 8 + 5] = a1.y; hraw[kc * 8 + 6] = a1.z; hraw[kc * 8 + 7] = a1.w;
    }
  }

  for (int it = 0; it < 8; ++it) {
    const int n = wid * 8 + it;
    const int itn = it < 7 ? it + 1 : 7;  // clamped prefetch index

    // --- snapshot current ef, issue next ef loads (full-iteration distance) ---
    float fe[16];
    fe[0] = efn[0].x; fe[1] = efn[0].y; fe[2] = efn[0].z; fe[3] = efn[0].w;
    fe[4] = efn[1].x; fe[5] = efn[1].y; fe[6] = efn[1].z; fe[7] = efn[1].w;
    fe[8] = efn[2].x; fe[9] = efn[2].y; fe[10] = efn[2].z; fe[11] = efn[2].w;
    fe[12] = efn[3].x; fe[13] = efn[3].y; fe[14] = efn[3].z; fe[15] = efn[3].w;
    {
      const float* er = ef + (ebase + itn * 16 + t) * 64 + q * 8;
      efn[0] = *reinterpret_cast<const float4*>(er);
      efn[1] = *reinterpret_cast<const float4*>(er + 4);
      efn[2] = *reinterpret_cast<const float4*>(er + 32);
      efn[3] = *reinterpret_cast<const float4*>(er + 36);
    }

    // --- fp32 attention logit (exact) ---
    float ap = 0.f;
    #pragma unroll
    for (int j = 0; j < 16; ++j) ap += fe[j] * vsl[j];
    ap += __shfl_xor(ap, 16);
    ap += __shfl_xor(ap, 32);
    float a = ap + cval;
    a = a > 0.f ? a : 0.01f * a;  // leaky_relu

    // --- e GEMM (operand-swapped): C[h=nt*16+4q+r][edge=t] ---
    const bf16x8 e0 = pack8(fe), e1 = pack8(fe + 8);
    bf16x8 af[6];
    {
      float eo[16];  // e_out[h = nt*16 + 4q + r], this lane's edge column t
      #pragma unroll
      for (int nt = 0; nt < 4; ++nt) {
        f32x4 c = {0.f, 0.f, 0.f, 0.f};
        c = MFMA(*reinterpret_cast<const bf16x8*>(&WeT[(nt * 16 + t) * 72 + q * 8]), e0, c);
        c = MFMA(*reinterpret_cast<const bf16x8*>(&WeT[(nt * 16 + t) * 72 + 32 + q * 8]), e1, c);
        #pragma unroll
        for (int r = 0; r < 4; ++r)
          eo[nt * 4 + r] = fmaxf(c[r] + beQ[nt][r], 0.f);
      }
      af[4] = pack8(eo);      // k' = 128 + q*8 + j  <-> h = (j>>2)*16+4q+(j&3)
      af[5] = pack8(eo + 8);  // k' = 160 + q*8 + j  <-> h = 32 + ...
    }

    // --- convert current nf gather -> A-frags (frees hraw) ---
    #pragma unroll
    for (int kc = 0; kc < 4; ++kc) af[kc] = pack8(hraw + kc * 8);

    // --- issue next iteration's nf gather (covered by m-GEMM + sparsemax) ---
    {
      const int sn = (itn < 4) ? __shfl(si0, 16 * itn + t)
                               : __shfl(si1, 16 * (itn - 4) + t);
      const float* hp = nf + (long)sn * 128 + q * 8;
      #pragma unroll
      for (int kc = 0; kc < 4; ++kc) {
        float4 a0 = *reinterpret_cast<const float4*>(hp + kc * 32);
        float4 a1 = *reinterpret_cast<const float4*>(hp + kc * 32 + 4);
        hraw[kc * 8 + 0] = a0.x; hraw[kc * 8 + 1] = a0.y; hraw[kc * 8 + 2] = a0.z; hraw[kc * 8 + 3] = a0.w;
        hraw[kc * 8 + 4] = a1.x; hraw[kc * 8 + 5] = a1.y; hraw[kc * 8 + 6] = a1.z; hraw[kc * 8 + 7] = a1.w;
      }
    }

    // --- m GEMM: m = relu([h_src | e_out] @ Wo + bo), C[edge=4q+r][h'=nt*16+t] ---
    f32x4 accM[4];
    #pragma unroll
    for (int nt = 0; nt < 4; ++nt) {
      f32x4 c = {0.f, 0.f, 0.f, 0.f};
      #pragma unroll
      for (int kc = 0; kc < 6; ++kc)
        c = MFMA(af[kc], *reinterpret_cast<const bf16x8*>(&WoT[(nt * 16 + t) * 200 + kc * 32 + q * 8]), c);
      #pragma unroll
      for (int r = 0; r < 4; ++r) c[r] = fmaxf(c[r] + boL[nt], 0.f);
      accM[nt] = c;
    }

    // --- sparsemax over 16 logits (bitonic sort desc across t) ---
    float z = a;
    #pragma unroll
    for (int k = 2; k <= 16; k <<= 1) {
      #pragma unroll
      for (int j = k >> 1; j > 0; j >>= 1) {
        float o = __shfl_xor(z, j);
        const bool upper = (t & j) != 0;
        const bool desc = (t & k) == 0;
        z = (upper != desc) ? fmaxf(z, o) : fminf(z, o);
      }
    }
    float cs = z;
    #pragma unroll
    for (int off = 1; off < 16; off <<= 1) {
      float o = __shfl_up(cs, off, 16);
      cs += (t >= off) ? o : 0.f;
    }
    const bool gt = 1.f + (float)(t + 1) * z > cs;
    float kf = gt ? (float)(t + 1) : 0.f;
    float sv = gt ? z : 0.f;
    #pragma unroll
    for (int m = 1; m < 16; m <<= 1) {
      kf = fmaxf(kf, __shfl_xor(kf, m));
      sv += __shfl_xor(sv, m);
    }
    const float tau = (sv - 1.f) / kf;
    const float alpha = fmaxf(a - tau, 0.f);  // own edge t

    // --- h_neigh = alpha^T . m ---
    float al[4];
    #pragma unroll
    for (int r = 0; r < 4; ++r) al[r] = __shfl(alpha, 4 * q + r);
    float p[4];
    #pragma unroll
    for (int nt = 0; nt < 4; ++nt) {
      p[nt] = al[0] * accM[nt][0] + al[1] * accM[nt][1] +
              al[2] * accM[nt][2] + al[3] * accM[nt][3];
      p[nt] += __shfl_xor(p[nt], 16);
      p[nt] += __shfl_xor(p[nt], 32);
    }
    const float pown = (q == 0) ? p[0] : (q == 1) ? p[1] : (q == 2) ? p[2] : p[3];
    hn_out[(long)n * 64 + lane] = pown;  // coalesced 256B/wave
  }
}

// ---------- K2: out = relu([h_dst | h_neigh] @ Wn + bn), in place ----------
extern "C" __global__ void __launch_bounds__(256, 3)
gteast_out(const float* __restrict__ nf, const float* __restrict__ Wn,
           const float* __restrict__ bn, float* __restrict__ out) {
  __shared__ unsigned short WnT[64 * 200];
  const int tid = threadIdx.x;
  for (int i = tid; i < 192 * 64; i += 256) {
    int k = i >> 6, nn = i & 63;
    WnT[nn * 200 + k] = f2bf(Wn[i]);
  }
  __syncthreads();

  const int lane = tid & 63, w = tid >> 6, q = lane >> 4, t = lane & 15;
  const int tile = blockIdx.x * 4 + w;  // 0..3127; 3125 active
  if (tile >= ND / 16) return;
  const int r0 = tile * 16;

  float bnL[4];
  #pragma unroll
  for (int nt = 0; nt < 4; ++nt) bnL[nt] = bn[nt * 16 + t];

  float raw[8];
  bf16x8 af[6];
  const float* hp = nf + (long)(r0 + t) * 128 + q * 8;
  #pragma unroll
  for (int kc = 0; kc < 4; ++kc) {
    float4 a0 = *reinterpret_cast<const float4*>(hp + kc * 32);
    float4 a1 = *reinterpret_cast<const float4*>(hp + kc * 32 + 4);
    raw[0] = a0.x; raw[1] = a0.y; raw[2] = a0.z; raw[3] = a0.w;
    raw[4] = a1.x; raw[5] = a1.y; raw[6] = a1.z; raw[7] = a1.w;
    af[kc] = pack8(raw);
  }
  const float* gp = out + (long)(r0 + t) * 64 + q * 8;  // h_neigh staged by K1
  #pragma unroll
  for (int kc = 0; kc < 2; ++kc) {
    float4 a0 = *reinterpret_cast<const float4*>(gp + kc * 32);
    float4 a1 = *reinterpret_cast<const float4*>(gp + kc * 32 + 4);
    raw[0] = a0.x; raw[1] = a0.y; raw[2] = a0.z; raw[3] = a0.w;
    raw[4] = a1.x; raw[5] = a1.y; raw[6] = a1.z; raw[7] = a1.w;
    af[4 + kc] = pack8(raw);
  }

  #pragma unroll
  for (int nt = 0; nt < 4; ++nt) {
    f32x4 c = {0.f, 0.f, 0.f, 0.f};
    #pragma unroll
    for (int kc = 0; kc < 6; ++kc)
      c = MFMA(af[kc], *reinterpret_cast<const bf16x8*>(&WnT[(nt * 16 + t) * 200 + kc * 32 + q * 8]), c);
    #pragma unroll
    for (int r = 0; r < 4; ++r)
      out[(long)(r0 + 4 * q + r) * 64 + nt * 16 + t] = fmaxf(c[r] + bnL[nt], 0.f);
  }
}

extern "C" void kernel_launch(void* const* d_in, const int* in_sizes, int n_in,
                              void* d_out, int out_size, void* d_ws, size_t ws_size,
                              hipStream_t stream) {
  const float* nf = (const float*)d_in[0];
  const float* ef = (const float*)d_in[1];
  const int* si   = (const int*)d_in[2];
  const float* We = (const float*)d_in[3];
  const float* be = (const float*)d_in[4];
  const float* Wa = (const float*)d_in[5];
  const float* ba = (const float*)d_in[6];
  const float* wa = (const float*)d_in[7];
  const float* Wo = (const float*)d_in[8];
  const float* bo = (const float*)d_in[9];
  const float* Wn = (const float*)d_in[10];
  const float* bn = (const float*)d_in[11];
  float* out = (float*)d_out;
  float* vc = (float*)d_ws;  // 65 floats

  gteast_prep<<<1, 256, 0, stream>>>(Wa, ba, wa, vc);
  gteast_edge<<<1563, 256, 0, stream>>>(nf, ef, si, We, be, Wo, bo, vc, out);
  gteast_out<<<782, 256, 0, stream>>>(nf, Wn, bn, out);
}

// Round 2
// 599.388 us; speedup vs baseline: 1.0944x; 1.0944x over previous
//
#include <hip/hip_runtime.h>

// GTEAST layer, round 5: Elds-free e-GEMM (operand swap), spill-free occupancy.
// N_SRC=100000, N_DST=50000, DEG=16, NODE_IN=128, EDGE_IN=64, HID=64, E=800000
// Fold: a = leaky_relu(ef @ (Wa@wa) + ba.wa)  (fp32, exact)
// GEMMs: bf16 v_mfma_f32_16x16x32_bf16, fp32 accum.
//   A-frag: lane q*16+t holds A[m=t][k=q*8+j]
//   B-frag: lane q*16+t holds B^T[n=t][k=q*8+j]  (from W^T rows in LDS)
//   C/D:    lane q*16+t holds C[row=q*4+reg][col=t]
// e-GEMM is computed OPERAND-SWAPPED: MFMA(WeT_frag, ef_frag) -> C[h][edge],
// so edge sits on the t index and e_out stays in registers as a valid m-GEMM
// A-frag under a k-row permutation of Wo (applied once at WoT staging):
//   k' = 128 + (h&32) + ((h>>2)&3)*8 + ((h>>4)&1)*4 + (h&3)   (bijective)
// Removes Elds (LDS 44544->35328), both per-iteration lgkmcnt(0) drains and
// 16 bank-conflicted ds_write_b16/iter.
// __launch_bounds__(256,3): round-4's (256,4) capped VGPR at 128 and spilled
// (+230MB scratch writes, 3x regression). 3 waves/EU leaves ~170 VGPR -> no
// spill; LDS still admits 4 blocks/CU if allocation lands <=128.
// One wave = 8 consecutive dsts (128 consecutive edges): src_idx batched via
// 2 coalesced ints/lane + per-iter shuffle; ef prefetched 1 iter ahead; nf
// gather issued before m-GEMM. h_neigh staged fp32 in d_out; K2 in place.

#define ND 50000

typedef __bf16 bf16x8 __attribute__((ext_vector_type(8)));
typedef float f32x4 __attribute__((ext_vector_type(4)));

// fp32 -> bf16 RNE (weights, one-time)
__device__ __forceinline__ unsigned short f2bf(float x) {
  unsigned u = __float_as_uint(x);
  u += 0x7fffu + ((u >> 16) & 1u);
  return (unsigned short)(u >> 16);
}

union Frag8 { bf16x8 v; unsigned u32[4]; };

// 8 floats -> bf16x8, round-half-up (+0x8000) + v_perm pack: ~1.5 VALU/elem
__device__ __forceinline__ bf16x8 pack8(const float* fr) {
  Frag8 f;
  #pragma unroll
  for (int j = 0; j < 4; ++j) {
    unsigned lo = __float_as_uint(fr[2 * j]) + 0x8000u;
    unsigned hi = __float_as_uint(fr[2 * j + 1]) + 0x8000u;
    f.u32[j] = __builtin_amdgcn_perm(hi, lo, 0x07060302);
  }
  return f.v;
}

#define MFMA(a, b, c) __builtin_amdgcn_mfma_f32_16x16x32_bf16((a), (b), (c), 0, 0, 0)

// ---------- K0: v = Wa@wa, c = ba.wa (256 threads, LDS reduce) ----------
extern "C" __global__ void gteast_prep(const float* __restrict__ Wa,
                                       const float* __restrict__ ba,
                                       const float* __restrict__ wa,
                                       float* __restrict__ vc) {
  __shared__ float red[260];
  const int tid = threadIdx.x, k = tid >> 2, p = tid & 3;
  float s = 0.f;
  for (int h = 16 * p; h < 16 * p + 16; ++h) s += Wa[k * 64 + h] * wa[h];
  red[tid] = s;
  if (tid < 4) {
    float sc = 0.f;
    for (int h = 16 * tid; h < 16 * tid + 16; ++h) sc += ba[h] * wa[h];
    red[256 + tid] = sc;
  }
  __syncthreads();
  if (p == 0) vc[k] = red[4 * k] + red[4 * k + 1] + red[4 * k + 2] + red[4 * k + 3];
  if (tid == 0) vc[64] = red[256] + red[257] + red[258] + red[259];
}

// ---------- K1: fused e_out + attention + m + sparsemax + h_neigh ----------
extern "C" __global__ void __launch_bounds__(256, 3)
gteast_edge(const float* __restrict__ nf, const float* __restrict__ ef,
            const int* __restrict__ src_idx,
            const float* __restrict__ We, const float* __restrict__ be,
            const float* __restrict__ Wo, const float* __restrict__ bo,
            const float* __restrict__ vc,
            float* __restrict__ hn_out) {
  __shared__ unsigned short WeT[64 * 72];   // We^T[n][k], stride 72 (16B rows)
  __shared__ unsigned short WoT[64 * 200];  // Wo^T[n][k'], k>=128 rows permuted
  __shared__ float vls[68];                 // v[64], c at [64]

  const int tid = threadIdx.x;
  for (int i = tid; i < 64 * 64; i += 256) {
    int k = i >> 6, n = i & 63;
    WeT[n * 72 + k] = f2bf(We[i]);
  }
  for (int i = tid; i < 192 * 64; i += 256) {
    int k = i >> 6, n = i & 63;
    int kk = k;
    if (k >= 128) {  // permute e_out k-rows to match register A-frag layout
      int h = k - 128;
      kk = 128 + (h & 32) + ((h >> 2) & 3) * 8 + ((h >> 4) & 1) * 4 + (h & 3);
    }
    WoT[n * 200 + kk] = f2bf(Wo[i]);
  }
  if (tid < 65) vls[tid] = vc[tid];
  __syncthreads();

  const int lane = tid & 63, w = tid >> 6;
  const int q = lane >> 4, t = lane & 15;
  const int wid = blockIdx.x * 4 + w;  // 0..6251; 6250 active
  if (wid * 8 >= ND) return;           // after the only __syncthreads

  const float cval = vls[64];
  float boL[4];
  float4 beQ[4];  // be[nt*16 + 4q + r] for the swapped e-GEMM epilogue
  #pragma unroll
  for (int nt = 0; nt < 4; ++nt) {
    boL[nt] = bo[nt * 16 + t];
    beQ[nt] = *reinterpret_cast<const float4*>(be + nt * 16 + 4 * q);
  }
  // logit vector slices (per-quad broadcast reads from LDS)
  float vsl[16];
  #pragma unroll
  for (int j = 0; j < 8; ++j) { vsl[j] = vls[q * 8 + j]; vsl[8 + j] = vls[32 + q * 8 + j]; }

  // batched src_idx: wave's 128 edges, 2 coalesced ints/lane
  const int si0 = src_idx[wid * 128 + lane];
  const int si1 = src_idx[wid * 128 + 64 + lane];

  const long ebase = (long)(wid * 128);

  // --- prologue: prefetch ef(it=0) and nf(it=0) ---
  float4 efn[4];
  {
    const float* er = ef + (ebase + t) * 64 + q * 8;
    efn[0] = *reinterpret_cast<const float4*>(er);
    efn[1] = *reinterpret_cast<const float4*>(er + 4);
    efn[2] = *reinterpret_cast<const float4*>(er + 32);
    efn[3] = *reinterpret_cast<const float4*>(er + 36);
  }
  float hraw[32];
  {
    const int s0 = __shfl(si0, t);
    const float* hp = nf + (long)s0 * 128 + q * 8;
    #pragma unroll
    for (int kc = 0; kc < 4; ++kc) {
      float4 a0 = *reinterpret_cast<const float4*>(hp + kc * 32);
      float4 a1 = *reinterpret_cast<const float4*>(hp + kc * 32 + 4);
      hraw[kc * 8 + 0] = a0.x; hraw[kc * 8 + 1] = a0.y; hraw[kc * 8 + 2] = a0.z; hraw[kc * 8 + 3] = a0.w;
      hraw[kc * 8 + 4] = a1.x; hraw[kc * 8 + 5] = a1.y; hraw[kc * 8 + 6] = a1.z; hraw[kc * 8 + 7] = a1.w;
    }
  }

  for (int it = 0; it < 8; ++it) {
    const int n = wid * 8 + it;
    const int itn = it < 7 ? it + 1 : 7;  // clamped prefetch index

    // --- snapshot current ef, issue next ef loads (full-iteration distance) ---
    float fe[16];
    fe[0] = efn[0].x; fe[1] = efn[0].y; fe[2] = efn[0].z; fe[3] = efn[0].w;
    fe[4] = efn[1].x; fe[5] = efn[1].y; fe[6] = efn[1].z; fe[7] = efn[1].w;
    fe[8] = efn[2].x; fe[9] = efn[2].y; fe[10] = efn[2].z; fe[11] = efn[2].w;
    fe[12] = efn[3].x; fe[13] = efn[3].y; fe[14] = efn[3].z; fe[15] = efn[3].w;
    {
      const float* er = ef + (ebase + itn * 16 + t) * 64 + q * 8;
      efn[0] = *reinterpret_cast<const float4*>(er);
      efn[1] = *reinterpret_cast<const float4*>(er + 4);
      efn[2] = *reinterpret_cast<const float4*>(er + 32);
      efn[3] = *reinterpret_cast<const float4*>(er + 36);
    }

    // --- fp32 attention logit (exact) ---
    float ap = 0.f;
    #pragma unroll
    for (int j = 0; j < 16; ++j) ap += fe[j] * vsl[j];
    ap += __shfl_xor(ap, 16);
    ap += __shfl_xor(ap, 32);
    float a = ap + cval;
    a = a > 0.f ? a : 0.01f * a;  // leaky_relu

    // --- e GEMM (operand-swapped): C[h=nt*16+4q+r][edge=t] ---
    const bf16x8 e0 = pack8(fe), e1 = pack8(fe + 8);
    bf16x8 af[6];
    {
      float eo[16];  // e_out[h = nt*16 + 4q + r], this lane's edge column t
      #pragma unroll
      for (int nt = 0; nt < 4; ++nt) {
        f32x4 c = {0.f, 0.f, 0.f, 0.f};
        c = MFMA(*reinterpret_cast<const bf16x8*>(&WeT[(nt * 16 + t) * 72 + q * 8]), e0, c);
        c = MFMA(*reinterpret_cast<const bf16x8*>(&WeT[(nt * 16 + t) * 72 + 32 + q * 8]), e1, c);
        #pragma unroll
        for (int r = 0; r < 4; ++r)
          eo[nt * 4 + r] = fmaxf(c[r] + beQ[nt][r], 0.f);
      }
      af[4] = pack8(eo);      // k' = 128 + q*8 + j  <-> h = (j>>2)*16+4q+(j&3)
      af[5] = pack8(eo + 8);  // k' = 160 + q*8 + j  <-> h = 32 + ...
    }

    // --- convert current nf gather -> A-frags (frees hraw) ---
    #pragma unroll
    for (int kc = 0; kc < 4; ++kc) af[kc] = pack8(hraw + kc * 8);

    // --- issue next iteration's nf gather (covered by m-GEMM + sparsemax) ---
    {
      const int sn = (itn < 4) ? __shfl(si0, 16 * itn + t)
                               : __shfl(si1, 16 * (itn - 4) + t);
      const float* hp = nf + (long)sn * 128 + q * 8;
      #pragma unroll
      for (int kc = 0; kc < 4; ++kc) {
        float4 a0 = *reinterpret_cast<const float4*>(hp + kc * 32);
        float4 a1 = *reinterpret_cast<const float4*>(hp + kc * 32 + 4);
        hraw[kc * 8 + 0] = a0.x; hraw[kc * 8 + 1] = a0.y; hraw[kc * 8 + 2] = a0.z; hraw[kc * 8 + 3] = a0.w;
        hraw[kc * 8 + 4] = a1.x; hraw[kc * 8 + 5] = a1.y; hraw[kc * 8 + 6] = a1.z; hraw[kc * 8 + 7] = a1.w;
      }
    }

    // --- m GEMM: m = relu([h_src | e_out] @ Wo + bo), C[edge=4q+r][h'=nt*16+t] ---
    f32x4 accM[4];
    #pragma unroll
    for (int nt = 0; nt < 4; ++nt) {
      f32x4 c = {0.f, 0.f, 0.f, 0.f};
      #pragma unroll
      for (int kc = 0; kc < 6; ++kc)
        c = MFMA(af[kc], *reinterpret_cast<const bf16x8*>(&WoT[(nt * 16 + t) * 200 + kc * 32 + q * 8]), c);
      #pragma unroll
      for (int r = 0; r < 4; ++r) c[r] = fmaxf(c[r] + boL[nt], 0.f);
      accM[nt] = c;
    }

    // --- sparsemax over 16 logits (bitonic sort desc across t) ---
    float z = a;
    #pragma unroll
    for (int k = 2; k <= 16; k <<= 1) {
      #pragma unroll
      for (int j = k >> 1; j > 0; j >>= 1) {
        float o = __shfl_xor(z, j);
        const bool upper = (t & j) != 0;
        const bool desc = (t & k) == 0;
        z = (upper != desc) ? fmaxf(z, o) : fminf(z, o);
      }
    }
    float cs = z;
    #pragma unroll
    for (int off = 1; off < 16; off <<= 1) {
      float o = __shfl_up(cs, off, 16);
      cs += (t >= off) ? o : 0.f;
    }
    const bool gt = 1.f + (float)(t + 1) * z > cs;
    float kf = gt ? (float)(t + 1) : 0.f;
    float sv = gt ? z : 0.f;
    #pragma unroll
    for (int m = 1; m < 16; m <<= 1) {
      kf = fmaxf(kf, __shfl_xor(kf, m));
      sv += __shfl_xor(sv, m);
    }
    const float tau = (sv - 1.f) / kf;
    const float alpha = fmaxf(a - tau, 0.f);  // own edge t

    // --- h_neigh = alpha^T . m ---
    float al[4];
    #pragma unroll
    for (int r = 0; r < 4; ++r) al[r] = __shfl(alpha, 4 * q + r);
    float p[4];
    #pragma unroll
    for (int nt = 0; nt < 4; ++nt) {
      p[nt] = al[0] * accM[nt][0] + al[1] * accM[nt][1] +
              al[2] * accM[nt][2] + al[3] * accM[nt][3];
      p[nt] += __shfl_xor(p[nt], 16);
      p[nt] += __shfl_xor(p[nt], 32);
    }
    const float pown = (q == 0) ? p[0] : (q == 1) ? p[1] : (q == 2) ? p[2] : p[3];
    hn_out[(long)n * 64 + lane] = pown;  // coalesced 256B/wave
  }
}

// ---------- K2: out = relu([h_dst | h_neigh] @ Wn + bn), in place ----------
extern "C" __global__ void __launch_bounds__(256, 3)
gteast_out(const float* __restrict__ nf, const float* __restrict__ Wn,
           const float* __restrict__ bn, float* __restrict__ out) {
  __shared__ unsigned short WnT[64 * 200];
  const int tid = threadIdx.x;
  for (int i = tid; i < 192 * 64; i += 256) {
    int k = i >> 6, nn = i & 63;
    WnT[nn * 200 + k] = f2bf(Wn[i]);
  }
  __syncthreads();

  const int lane = tid & 63, w = tid >> 6, q = lane >> 4, t = lane & 15;
  const int tile = blockIdx.x * 4 + w;  // 0..3127; 3125 active
  if (tile >= ND / 16) return;
  const int r0 = tile * 16;

  float bnL[4];
  #pragma unroll
  for (int nt = 0; nt < 4; ++nt) bnL[nt] = bn[nt * 16 + t];

  float raw[8];
  bf16x8 af[6];
  const float* hp = nf + (long)(r0 + t) * 128 + q * 8;
  #pragma unroll
  for (int kc = 0; kc < 4; ++kc) {
    float4 a0 = *reinterpret_cast<const float4*>(hp + kc * 32);
    float4 a1 = *reinterpret_cast<const float4*>(hp + kc * 32 + 4);
    raw[0] = a0.x; raw[1] = a0.y; raw[2] = a0.z; raw[3] = a0.w;
    raw[4] = a1.x; raw[5] = a1.y; raw[6] = a1.z; raw[7] = a1.w;
    af[kc] = pack8(raw);
  }
  const float* gp = out + (long)(r0 + t) * 64 + q * 8;  // h_neigh staged by K1
  #pragma unroll
  for (int kc = 0; kc < 2; ++kc) {
    float4 a0 = *reinterpret_cast<const float4*>(gp + kc * 32);
    float4 a1 = *reinterpret_cast<const float4*>(gp + kc * 32 + 4);
    raw[0] = a0.x; raw[1] = a0.y; raw[2] = a0.z; raw[3] = a0.w;
    raw[4] = a1.x; raw[5] = a1.y; raw[6] = a1.z; raw[7] = a1.w;
    af[4 + kc] = pack8(raw);
  }

  #pragma unroll
  for (int nt = 0; nt < 4; ++nt) {
    f32x4 c = {0.f, 0.f, 0.f, 0.f};
    #pragma unroll
    for (int kc = 0; kc < 6; ++kc)
      c = MFMA(af[kc], *reinterpret_cast<const bf16x8*>(&WnT[(nt * 16 + t) * 200 + kc * 32 + q * 8]), c);
    #pragma unroll
    for (int r = 0; r < 4; ++r)
      out[(long)(r0 + 4 * q + r) * 64 + nt * 16 + t] = fmaxf(c[r] + bnL[nt], 0.f);
  }
}

extern "C" void kernel_launch(void* const* d_in, const int* in_sizes, int n_in,
                              void* d_out, int out_size, void* d_ws, size_t ws_size,
                              hipStream_t stream) {
  const float* nf = (const float*)d_in[0];
  const float* ef = (const float*)d_in[1];
  const int* si   = (const int*)d_in[2];
  const float* We = (const float*)d_in[3];
  const float* be = (const float*)d_in[4];
  const float* Wa = (const float*)d_in[5];
  const float* ba = (const float*)d_in[6];
  const float* wa = (const float*)d_in[7];
  const float* Wo = (const float*)d_in[8];
  const float* bo = (const float*)d_in[9];
  const float* Wn = (const float*)d_in[10];
  const float* bn = (const float*)d_in[11];
  float* out = (float*)d_out;
  float* vc = (float*)d_ws;  // 65 floats

  gteast_prep<<<1, 256, 0, stream>>>(Wa, ba, wa, vc);
  gteast_edge<<<1563, 256, 0, stream>>>(nf, ef, si, We, be, Wo, bo, vc, out);
  gteast_out<<<782, 256, 0, stream>>>(nf, Wn, bn, out);
}

// Round 3
// 410.693 us; speedup vs baseline: 1.5973x; 1.4595x over previous
//
#include <hip/hip_runtime.h>

// GTEAST layer, round 6: round-3 structure (proven 137us, zero spill) with
// We B-frags hoisted to registers and the WeT LDS region aliased with Elds.
// N_SRC=100000, N_DST=50000, DEG=16, NODE_IN=128, EDGE_IN=64, HID=64, E=800000
// Fold: a = leaky_relu(ef @ (Wa@wa) + ba.wa)  (fp32, exact)
// GEMMs: bf16 v_mfma_f32_16x16x32_bf16, fp32 accum.
//   A-frag: lane q*16+t holds A[m=t][k=q*8+j]
//   B-frag: lane q*16+t holds B^T[n=t][k=q*8+j]  (from W^T rows in LDS)
//   C/D:    lane q*16+t holds C[row=q*4+reg][col=t]
// Round-4/5 lesson: the Elds-free operand-swap structure spills to scratch
// (+170-230MB HBM writes) under any launch bound -> reverted. The LDS
// round-trip splits live ranges and keeps the allocator at ~80 VGPR.
// This round: WeE[64*72] LDS is staged with We^T, each lane loads its 8
// loop-invariant e-GEMM B-frags (bf16x8, +32 VGPR), then the SAME region is
// reused as the per-wave Elds e_out tile (both 9216B; WeT consumed before
// the loop). LDS 44544 -> 35328 => 4 blocks/CU (16 waves, was 3/12).
// One wave = 8 consecutive dsts (128 consecutive edges): src_idx batched via
// 2 coalesced ints/lane + per-iter shuffle; ef prefetched 1 iter ahead; nf
// gather issued before m-GEMM. h_neigh staged fp32 in d_out; K2 in place.

#define ND 50000

typedef __bf16 bf16x8 __attribute__((ext_vector_type(8)));
typedef float f32x4 __attribute__((ext_vector_type(4)));

__device__ __forceinline__ void sync_wave() {
  asm volatile("s_waitcnt lgkmcnt(0)" ::: "memory");
}

// fp32 -> bf16 RNE (weights, one-time)
__device__ __forceinline__ unsigned short f2bf(float x) {
  unsigned u = __float_as_uint(x);
  u += 0x7fffu + ((u >> 16) & 1u);
  return (unsigned short)(u >> 16);
}

union Frag8 { bf16x8 v; unsigned u32[4]; };

// 8 floats -> bf16x8, round-half-up (+0x8000) + v_perm pack: ~1.5 VALU/elem
__device__ __forceinline__ bf16x8 pack8(const float* fr) {
  Frag8 f;
  #pragma unroll
  for (int j = 0; j < 4; ++j) {
    unsigned lo = __float_as_uint(fr[2 * j]) + 0x8000u;
    unsigned hi = __float_as_uint(fr[2 * j + 1]) + 0x8000u;
    f.u32[j] = __builtin_amdgcn_perm(hi, lo, 0x07060302);
  }
  return f.v;
}

#define MFMA(a, b, c) __builtin_amdgcn_mfma_f32_16x16x32_bf16((a), (b), (c), 0, 0, 0)

// ---------- K0: v = Wa@wa, c = ba.wa (256 threads, LDS reduce) ----------
extern "C" __global__ void gteast_prep(const float* __restrict__ Wa,
                                       const float* __restrict__ ba,
                                       const float* __restrict__ wa,
                                       float* __restrict__ vc) {
  __shared__ float red[260];
  const int tid = threadIdx.x, k = tid >> 2, p = tid & 3;
  float s = 0.f;
  for (int h = 16 * p; h < 16 * p + 16; ++h) s += Wa[k * 64 + h] * wa[h];
  red[tid] = s;
  if (tid < 4) {
    float sc = 0.f;
    for (int h = 16 * tid; h < 16 * tid + 16; ++h) sc += ba[h] * wa[h];
    red[256 + tid] = sc;
  }
  __syncthreads();
  if (p == 0) vc[k] = red[4 * k] + red[4 * k + 1] + red[4 * k + 2] + red[4 * k + 3];
  if (tid == 0) vc[64] = red[256] + red[257] + red[258] + red[259];
}

// ---------- K1: fused e_out + attention + m + sparsemax + h_neigh ----------
extern "C" __global__ void __launch_bounds__(256, 3)
gteast_edge(const float* __restrict__ nf, const float* __restrict__ ef,
            const int* __restrict__ src_idx,
            const float* __restrict__ We, const float* __restrict__ be,
            const float* __restrict__ Wo, const float* __restrict__ bo,
            const float* __restrict__ vc,
            float* __restrict__ hn_out) {
  __shared__ unsigned short WoT[64 * 200];  // Wo^T[n][k], stride 200
  __shared__ unsigned short WeE[64 * 72];   // phase 1: We^T[n][k] stage;
                                            // phase 2: Elds[4][16*72] e_out tiles
  __shared__ float vls[68];                 // v[64], c at [64]

  const int tid = threadIdx.x;
  for (int i = tid; i < 64 * 64; i += 256) {
    int k = i >> 6, n = i & 63;
    WeE[n * 72 + k] = f2bf(We[i]);
  }
  for (int i = tid; i < 192 * 64; i += 256) {
    int k = i >> 6, n = i & 63;
    WoT[n * 200 + k] = f2bf(Wo[i]);
  }
  if (tid < 65) vls[tid] = vc[tid];
  __syncthreads();

  const int lane = tid & 63, w = tid >> 6;
  const int q = lane >> 4, t = lane & 15;
  const int wid = blockIdx.x * 4 + w;  // 0..6251; 6250 active

  // loop-invariant e-GEMM B-frags (We^T rows) -> registers, then free WeE
  bf16x8 weF[8];
  #pragma unroll
  for (int nt = 0; nt < 4; ++nt) {
    weF[2 * nt]     = *reinterpret_cast<const bf16x8*>(&WeE[(nt * 16 + t) * 72 + q * 8]);
    weF[2 * nt + 1] = *reinterpret_cast<const bf16x8*>(&WeE[(nt * 16 + t) * 72 + 32 + q * 8]);
  }
  __syncthreads();  // WeE fully consumed; region becomes Elds

  if (wid * 8 >= ND) return;  // after both barriers

  unsigned short* E = &WeE[w * (16 * 72)];  // this wave's e_out tile [m][h]
  const float cval = vls[64];
  float beL[4], boL[4];
  #pragma unroll
  for (int nt = 0; nt < 4; ++nt) { beL[nt] = be[nt * 16 + t]; boL[nt] = bo[nt * 16 + t]; }
  // logit vector slices (per-quad broadcast reads from LDS)
  float vsl[16];
  #pragma unroll
  for (int j = 0; j < 8; ++j) { vsl[j] = vls[q * 8 + j]; vsl[8 + j] = vls[32 + q * 8 + j]; }

  // batched src_idx: wave's 128 edges, 2 coalesced ints/lane
  const int si0 = src_idx[wid * 128 + lane];
  const int si1 = src_idx[wid * 128 + 64 + lane];

  const long ebase = (long)(wid * 128);

  // --- prologue: prefetch ef(it=0) and nf(it=0) ---
  float4 efn[4];
  {
    const float* er = ef + (ebase + t) * 64 + q * 8;
    efn[0] = *reinterpret_cast<const float4*>(er);
    efn[1] = *reinterpret_cast<const float4*>(er + 4);
    efn[2] = *reinterpret_cast<const float4*>(er + 32);
    efn[3] = *reinterpret_cast<const float4*>(er + 36);
  }
  float hraw[32];
  {
    const int s0 = __shfl(si0, t);
    const float* hp = nf + (long)s0 * 128 + q * 8;
    #pragma unroll
    for (int kc = 0; kc < 4; ++kc) {
      float4 a0 = *reinterpret_cast<const float4*>(hp + kc * 32);
      float4 a1 = *reinterpret_cast<const float4*>(hp + kc * 32 + 4);
      hraw[kc * 8 + 0] = a0.x; hraw[kc * 8 + 1] = a0.y; hraw[kc * 8 + 2] = a0.z; hraw[kc * 8 + 3] = a0.w;
      hraw[kc * 8 + 4] = a1.x; hraw[kc * 8 + 5] = a1.y; hraw[kc * 8 + 6] = a1.z; hraw[kc * 8 + 7] = a1.w;
    }
  }

  for (int it = 0; it < 8; ++it) {
    const int n = wid * 8 + it;
    const int itn = it < 7 ? it + 1 : 7;  // clamped prefetch index

    // --- snapshot current ef, issue next ef loads (full-iteration distance) ---
    float fe[16];
    fe[0] = efn[0].x; fe[1] = efn[0].y; fe[2] = efn[0].z; fe[3] = efn[0].w;
    fe[4] = efn[1].x; fe[5] = efn[1].y; fe[6] = efn[1].z; fe[7] = efn[1].w;
    fe[8] = efn[2].x; fe[9] = efn[2].y; fe[10] = efn[2].z; fe[11] = efn[2].w;
    fe[12] = efn[3].x; fe[13] = efn[3].y; fe[14] = efn[3].z; fe[15] = efn[3].w;
    {
      const float* er = ef + (ebase + itn * 16 + t) * 64 + q * 8;
      efn[0] = *reinterpret_cast<const float4*>(er);
      efn[1] = *reinterpret_cast<const float4*>(er + 4);
      efn[2] = *reinterpret_cast<const float4*>(er + 32);
      efn[3] = *reinterpret_cast<const float4*>(er + 36);
    }

    // --- fp32 attention logit (exact) ---
    float ap = 0.f;
    #pragma unroll
    for (int j = 0; j < 16; ++j) ap += fe[j] * vsl[j];
    ap += __shfl_xor(ap, 16);
    ap += __shfl_xor(ap, 32);
    float a = ap + cval;
    a = a > 0.f ? a : 0.01f * a;  // leaky_relu

    // --- e GEMM: e_out = relu(ef @ We + be), B-frags from registers ---
    const bf16x8 e0 = pack8(fe), e1 = pack8(fe + 8);
    #pragma unroll
    for (int nt = 0; nt < 4; ++nt) {
      f32x4 c = {0.f, 0.f, 0.f, 0.f};
      c = MFMA(e0, weF[2 * nt], c);
      c = MFMA(e1, weF[2 * nt + 1], c);
      #pragma unroll
      for (int r = 0; r < 4; ++r) {
        float vv = fmaxf(c[r] + beL[nt], 0.f);
        E[(4 * q + r) * 72 + nt * 16 + t] = f2bf(vv);
      }
    }
    sync_wave();

    // --- convert current nf gather -> A-frags (frees hraw) ---
    bf16x8 af[6];
    #pragma unroll
    for (int kc = 0; kc < 4; ++kc) af[kc] = pack8(hraw + kc * 8);
    af[4] = *reinterpret_cast<const bf16x8*>(&E[t * 72 + q * 8]);
    af[5] = *reinterpret_cast<const bf16x8*>(&E[t * 72 + 32 + q * 8]);

    // --- issue next iteration's nf gather (covered by m-GEMM + sparsemax) ---
    {
      const int sn = (itn < 4) ? __shfl(si0, 16 * itn + t)
                               : __shfl(si1, 16 * (itn - 4) + t);
      const float* hp = nf + (long)sn * 128 + q * 8;
      #pragma unroll
      for (int kc = 0; kc < 4; ++kc) {
        float4 a0 = *reinterpret_cast<const float4*>(hp + kc * 32);
        float4 a1 = *reinterpret_cast<const float4*>(hp + kc * 32 + 4);
        hraw[kc * 8 + 0] = a0.x; hraw[kc * 8 + 1] = a0.y; hraw[kc * 8 + 2] = a0.z; hraw[kc * 8 + 3] = a0.w;
        hraw[kc * 8 + 4] = a1.x; hraw[kc * 8 + 5] = a1.y; hraw[kc * 8 + 6] = a1.z; hraw[kc * 8 + 7] = a1.w;
      }
    }

    // --- m GEMM: m = relu([h_src | e_out] @ Wo + bo) ---
    f32x4 accM[4];
    #pragma unroll
    for (int nt = 0; nt < 4; ++nt) {
      f32x4 c = {0.f, 0.f, 0.f, 0.f};
      #pragma unroll
      for (int kc = 0; kc < 6; ++kc)
        c = MFMA(af[kc], *reinterpret_cast<const bf16x8*>(&WoT[(nt * 16 + t) * 200 + kc * 32 + q * 8]), c);
      #pragma unroll
      for (int r = 0; r < 4; ++r) c[r] = fmaxf(c[r] + boL[nt], 0.f);
      accM[nt] = c;
    }
    sync_wave();  // E reads drained before next iteration's writes

    // --- sparsemax over 16 logits (bitonic sort desc across t) ---
    float z = a;
    #pragma unroll
    for (int k = 2; k <= 16; k <<= 1) {
      #pragma unroll
      for (int j = k >> 1; j > 0; j >>= 1) {
        float o = __shfl_xor(z, j);
        const bool upper = (t & j) != 0;
        const bool desc = (t & k) == 0;
        z = (upper != desc) ? fmaxf(z, o) : fminf(z, o);
      }
    }
    float cs = z;
    #pragma unroll
    for (int off = 1; off < 16; off <<= 1) {
      float o = __shfl_up(cs, off, 16);
      cs += (t >= off) ? o : 0.f;
    }
    const bool gt = 1.f + (float)(t + 1) * z > cs;
    float kf = gt ? (float)(t + 1) : 0.f;
    float sv = gt ? z : 0.f;
    #pragma unroll
    for (int m = 1; m < 16; m <<= 1) {
      kf = fmaxf(kf, __shfl_xor(kf, m));
      sv += __shfl_xor(sv, m);
    }
    const float tau = (sv - 1.f) / kf;
    const float alpha = fmaxf(a - tau, 0.f);  // own edge t

    // --- h_neigh = alpha^T . m ---
    float al[4];
    #pragma unroll
    for (int r = 0; r < 4; ++r) al[r] = __shfl(alpha, 4 * q + r);
    float p[4];
    #pragma unroll
    for (int nt = 0; nt < 4; ++nt) {
      p[nt] = al[0] * accM[nt][0] + al[1] * accM[nt][1] +
              al[2] * accM[nt][2] + al[3] * accM[nt][3];
      p[nt] += __shfl_xor(p[nt], 16);
      p[nt] += __shfl_xor(p[nt], 32);
    }
    const float pown = (q == 0) ? p[0] : (q == 1) ? p[1] : (q == 2) ? p[2] : p[3];
    hn_out[(long)n * 64 + lane] = pown;  // coalesced 256B/wave
  }
}

// ---------- K2: out = relu([h_dst | h_neigh] @ Wn + bn), in place ----------
extern "C" __global__ void __launch_bounds__(256, 3)
gteast_out(const float* __restrict__ nf, const float* __restrict__ Wn,
           const float* __restrict__ bn, float* __restrict__ out) {
  __shared__ unsigned short WnT[64 * 200];
  const int tid = threadIdx.x;
  for (int i = tid; i < 192 * 64; i += 256) {
    int k = i >> 6, nn = i & 63;
    WnT[nn * 200 + k] = f2bf(Wn[i]);
  }
  __syncthreads();

  const int lane = tid & 63, w = tid >> 6, q = lane >> 4, t = lane & 15;
  const int tile = blockIdx.x * 4 + w;  // 0..3127; 3125 active
  if (tile >= ND / 16) return;
  const int r0 = tile * 16;

  float bnL[4];
  #pragma unroll
  for (int nt = 0; nt < 4; ++nt) bnL[nt] = bn[nt * 16 + t];

  float raw[8];
  bf16x8 af[6];
  const float* hp = nf + (long)(r0 + t) * 128 + q * 8;
  #pragma unroll
  for (int kc = 0; kc < 4; ++kc) {
    float4 a0 = *reinterpret_cast<const float4*>(hp + kc * 32);
    float4 a1 = *reinterpret_cast<const float4*>(hp + kc * 32 + 4);
    raw[0] = a0.x; raw[1] = a0.y; raw[2] = a0.z; raw[3] = a0.w;
    raw[4] = a1.x; raw[5] = a1.y; raw[6] = a1.z; raw[7] = a1.w;
    af[kc] = pack8(raw);
  }
  const float* gp = out + (long)(r0 + t) * 64 + q * 8;  // h_neigh staged by K1
  #pragma unroll
  for (int kc = 0; kc < 2; ++kc) {
    float4 a0 = *reinterpret_cast<const float4*>(gp + kc * 32);
    float4 a1 = *reinterpret_cast<const float4*>(gp + kc * 32 + 4);
    raw[0] = a0.x; raw[1] = a0.y; raw[2] = a0.z; raw[3] = a0.w;
    raw[4] = a1.x; raw[5] = a1.y; raw[6] = a1.z; raw[7] = a1.w;
    af[4 + kc] = pack8(raw);
  }

  #pragma unroll
  for (int nt = 0; nt < 4; ++nt) {
    f32x4 c = {0.f, 0.f, 0.f, 0.f};
    #pragma unroll
    for (int kc = 0; kc < 6; ++kc)
      c = MFMA(af[kc], *reinterpret_cast<const bf16x8*>(&WnT[(nt * 16 + t) * 200 + kc * 32 + q * 8]), c);
    #pragma unroll
    for (int r = 0; r < 4; ++r)
      out[(long)(r0 + 4 * q + r) * 64 + nt * 16 + t] = fmaxf(c[r] + bnL[nt], 0.f);
  }
}

extern "C" void kernel_launch(void* const* d_in, const int* in_sizes, int n_in,
                              void* d_out, int out_size, void* d_ws, size_t ws_size,
                              hipStream_t stream) {
  const float* nf = (const float*)d_in[0];
  const float* ef = (const float*)d_in[1];
  const int* si   = (const int*)d_in[2];
  const float* We = (const float*)d_in[3];
  const float* be = (const float*)d_in[4];
  const float* Wa = (const float*)d_in[5];
  const float* ba = (const float*)d_in[6];
  const float* wa = (const float*)d_in[7];
  const float* Wo = (const float*)d_in[8];
  const float* bo = (const float*)d_in[9];
  const float* Wn = (const float*)d_in[10];
  const float* bn = (const float*)d_in[11];
  float* out = (float*)d_out;
  float* vc = (float*)d_ws;  // 65 floats

  gteast_prep<<<1, 256, 0, stream>>>(Wa, ba, wa, vc);
  gteast_edge<<<1563, 256, 0, stream>>>(nf, ef, si, We, be, Wo, bo, vc, out);
  gteast_out<<<782, 256, 0, stream>>>(nf, Wn, bn, out);
}

// Round 4
// 373.493 us; speedup vs baseline: 1.7564x; 1.0996x over previous
//
#include <hip/hip_runtime.h>

// GTEAST layer, round 7: algebraic gather reduction.
//   m = relu([h_src|e_out]@Wo + bo) = relu( y[src] + e_out@Wo_lo + bo ),
//   y = nf@Wo_up precomputed per SOURCE node (used ~8x) by gteast_src,
//   stored bf16 (100000x64, 12.8MB) in workspace.
// Edge kernel: gather drops 8KB->2KB per wave-iter (512B fp32 rows -> 16 u16),
// m-GEMM 24->8 MFMA, no hraw packs, LDS 44.5K->27.9K (5 blocks/CU ceiling).
// Sparsemax: count-based (c_t=#{z_j>=z_t}, s_t=sum{z_j>=z_t}; condition
// 1+c*z>s at tie-group ends is exactly the sorted criterion; max-reduce on c
// carrying s) -> ~9 serial bpermute stages vs ~18 for bitonic sort.
// Lessons kept: NO invariant-frag hoisting (rounds 4/5/6 all spilled);
// E LDS round-trip retained (splits live ranges, proven 80-84 VGPR).
// Fallback: if ws_size can't hold y, launch round-3 edge kernel verbatim.

#define ND 50000
#define NS 100000

typedef __bf16 bf16x8 __attribute__((ext_vector_type(8)));
typedef float f32x4 __attribute__((ext_vector_type(4)));

__device__ __forceinline__ void sync_wave() {
  asm volatile("s_waitcnt lgkmcnt(0)" ::: "memory");
}

// fp32 -> bf16 RNE
__device__ __forceinline__ unsigned short f2bf(float x) {
  unsigned u = __float_as_uint(x);
  u += 0x7fffu + ((u >> 16) & 1u);
  return (unsigned short)(u >> 16);
}
__device__ __forceinline__ float bf2f(unsigned short u) {
  return __uint_as_float((unsigned)u << 16);
}

union Frag8 { bf16x8 v; unsigned u32[4]; };

// 8 floats -> bf16x8, round-half-up (+0x8000) + v_perm pack
__device__ __forceinline__ bf16x8 pack8(const float* fr) {
  Frag8 f;
  #pragma unroll
  for (int j = 0; j < 4; ++j) {
    unsigned lo = __float_as_uint(fr[2 * j]) + 0x8000u;
    unsigned hi = __float_as_uint(fr[2 * j + 1]) + 0x8000u;
    f.u32[j] = __builtin_amdgcn_perm(hi, lo, 0x07060302);
  }
  return f.v;
}

#define MFMA(a, b, c) __builtin_amdgcn_mfma_f32_16x16x32_bf16((a), (b), (c), 0, 0, 0)

// ---------- K0: v = Wa@wa, c = ba.wa ----------
extern "C" __global__ void gteast_prep(const float* __restrict__ Wa,
                                       const float* __restrict__ ba,
                                       const float* __restrict__ wa,
                                       float* __restrict__ vc) {
  __shared__ float red[260];
  const int tid = threadIdx.x, k = tid >> 2, p = tid & 3;
  float s = 0.f;
  for (int h = 16 * p; h < 16 * p + 16; ++h) s += Wa[k * 64 + h] * wa[h];
  red[tid] = s;
  if (tid < 4) {
    float sc = 0.f;
    for (int h = 16 * tid; h < 16 * tid + 16; ++h) sc += ba[h] * wa[h];
    red[256 + tid] = sc;
  }
  __syncthreads();
  if (p == 0) vc[k] = red[4 * k] + red[4 * k + 1] + red[4 * k + 2] + red[4 * k + 3];
  if (tid == 0) vc[64] = red[256] + red[257] + red[258] + red[259];
}

// ---------- K_y: y = nf @ Wo[0:128] (bf16 out), per-source precompute ----------
extern "C" __global__ void __launch_bounds__(256, 3)
gteast_src(const float* __restrict__ nf, const float* __restrict__ Wo,
           unsigned short* __restrict__ y) {
  __shared__ unsigned short WuT[64 * 136];  // WoUp^T[h][k], stride 136
  const int tid = threadIdx.x;
  for (int i = tid; i < 128 * 64; i += 256) {
    int k = i >> 6, n = i & 63;
    WuT[n * 136 + k] = f2bf(Wo[i]);
  }
  __syncthreads();

  const int lane = tid & 63, w = tid >> 6, q = lane >> 4, t = lane & 15;
  const int tile = blockIdx.x * 4 + w;  // 6250 tiles
  if (tile >= NS / 16) return;
  const int r0 = tile * 16;

  float raw[8];
  bf16x8 af[4];
  const float* hp = nf + (long)(r0 + t) * 128 + q * 8;
  #pragma unroll
  for (int kc = 0; kc < 4; ++kc) {
    float4 a0 = *reinterpret_cast<const float4*>(hp + kc * 32);
    float4 a1 = *reinterpret_cast<const float4*>(hp + kc * 32 + 4);
    raw[0] = a0.x; raw[1] = a0.y; raw[2] = a0.z; raw[3] = a0.w;
    raw[4] = a1.x; raw[5] = a1.y; raw[6] = a1.z; raw[7] = a1.w;
    af[kc] = pack8(raw);
  }
  #pragma unroll
  for (int nt = 0; nt < 4; ++nt) {
    f32x4 c = {0.f, 0.f, 0.f, 0.f};
    #pragma unroll
    for (int kc = 0; kc < 4; ++kc)
      c = MFMA(af[kc], *reinterpret_cast<const bf16x8*>(&WuT[(nt * 16 + t) * 136 + kc * 32 + q * 8]), c);
    #pragma unroll
    for (int r = 0; r < 4; ++r)
      y[(long)(r0 + 4 * q + r) * 64 + nt * 16 + t] = f2bf(c[r]);
  }
}

// ---------- K1: fused e_out + attention + m + sparsemax + h_neigh ----------
extern "C" __global__ void __launch_bounds__(256, 3)
gteast_edge(const float* __restrict__ ef, const int* __restrict__ src_idx,
            const float* __restrict__ We, const float* __restrict__ be,
            const float* __restrict__ Wo, const float* __restrict__ bo,
            const float* __restrict__ vc, const unsigned short* __restrict__ y,
            float* __restrict__ hn_out) {
  __shared__ unsigned short WeT[64 * 72];      // We^T[n][k]
  __shared__ unsigned short WoLoT[64 * 72];    // Wo^T rows 128..191 (e_out part)
  __shared__ unsigned short Elds[4][16 * 72];  // per-wave e_out tile [m][h]
  __shared__ float vls[68];                    // v[64], c at [64]

  const int tid = threadIdx.x;
  for (int i = tid; i < 64 * 64; i += 256) {
    int k = i >> 6, n = i & 63;
    WeT[n * 72 + k] = f2bf(We[i]);
  }
  for (int i = tid; i < 64 * 64; i += 256) {
    int k = i >> 6, n = i & 63;
    WoLoT[n * 72 + k] = f2bf(Wo[(128 + k) * 64 + n]);
  }
  if (tid < 65) vls[tid] = vc[tid];
  __syncthreads();

  const int lane = tid & 63, w = tid >> 6;
  const int q = lane >> 4, t = lane & 15;
  const int wid = blockIdx.x * 4 + w;  // 6250 active
  if (wid * 8 >= ND) return;           // after the only __syncthreads

  unsigned short* E = Elds[w];
  const float cval = vls[64];
  float beL[4], boL[4];
  #pragma unroll
  for (int nt = 0; nt < 4; ++nt) { beL[nt] = be[nt * 16 + t]; boL[nt] = bo[nt * 16 + t]; }
  float vsl[16];
  #pragma unroll
  for (int j = 0; j < 8; ++j) { vsl[j] = vls[q * 8 + j]; vsl[8 + j] = vls[32 + q * 8 + j]; }

  const int si0 = src_idx[wid * 128 + lane];
  const int si1 = src_idx[wid * 128 + 64 + lane];

  const long ebase = (long)(wid * 128);

  // --- prologue: prefetch ef(0) and y(0) ---
  float4 efn[4];
  {
    const float* er = ef + (ebase + t) * 64 + q * 8;
    efn[0] = *reinterpret_cast<const float4*>(er);
    efn[1] = *reinterpret_cast<const float4*>(er + 4);
    efn[2] = *reinterpret_cast<const float4*>(er + 32);
    efn[3] = *reinterpret_cast<const float4*>(er + 36);
  }
  unsigned short yv[16];  // y[src(edge 4q+r)][nt*16+t]
  #pragma unroll
  for (int r = 0; r < 4; ++r) {
    const int s0 = __shfl(si0, 4 * q + r);
    const unsigned short* yp = y + (long)s0 * 64 + t;
    #pragma unroll
    for (int nt = 0; nt < 4; ++nt) yv[r * 4 + nt] = yp[nt * 16];
  }

  for (int it = 0; it < 8; ++it) {
    const int n = wid * 8 + it;
    const int itn = it < 7 ? it + 1 : 7;

    // --- snapshot current ef, issue next ef loads ---
    float fe[16];
    fe[0] = efn[0].x; fe[1] = efn[0].y; fe[2] = efn[0].z; fe[3] = efn[0].w;
    fe[4] = efn[1].x; fe[5] = efn[1].y; fe[6] = efn[1].z; fe[7] = efn[1].w;
    fe[8] = efn[2].x; fe[9] = efn[2].y; fe[10] = efn[2].z; fe[11] = efn[2].w;
    fe[12] = efn[3].x; fe[13] = efn[3].y; fe[14] = efn[3].z; fe[15] = efn[3].w;
    {
      const float* er = ef + (ebase + itn * 16 + t) * 64 + q * 8;
      efn[0] = *reinterpret_cast<const float4*>(er);
      efn[1] = *reinterpret_cast<const float4*>(er + 4);
      efn[2] = *reinterpret_cast<const float4*>(er + 32);
      efn[3] = *reinterpret_cast<const float4*>(er + 36);
    }

    // --- fp32 attention logit (exact) ---
    float ap = 0.f;
    #pragma unroll
    for (int j = 0; j < 16; ++j) ap += fe[j] * vsl[j];
    ap += __shfl_xor(ap, 16);
    ap += __shfl_xor(ap, 32);
    float a = ap + cval;
    a = a > 0.f ? a : 0.01f * a;  // leaky_relu

    // --- e GEMM: e_out = relu(ef @ We + be) ---
    const bf16x8 e0 = pack8(fe), e1 = pack8(fe + 8);
    #pragma unroll
    for (int nt = 0; nt < 4; ++nt) {
      f32x4 c = {0.f, 0.f, 0.f, 0.f};
      c = MFMA(e0, *reinterpret_cast<const bf16x8*>(&WeT[(nt * 16 + t) * 72 + q * 8]), c);
      c = MFMA(e1, *reinterpret_cast<const bf16x8*>(&WeT[(nt * 16 + t) * 72 + 32 + q * 8]), c);
      #pragma unroll
      for (int r = 0; r < 4; ++r) {
        float vv = fmaxf(c[r] + beL[nt], 0.f);
        E[(4 * q + r) * 72 + nt * 16 + t] = f2bf(vv);
      }
    }
    sync_wave();

    // --- e_out A-frags from E ---
    bf16x8 af4 = *reinterpret_cast<const bf16x8*>(&E[t * 72 + q * 8]);
    bf16x8 af5 = *reinterpret_cast<const bf16x8*>(&E[t * 72 + 32 + q * 8]);

    // --- m GEMM: m = relu(y[src] + e_out @ Wo_lo + bo), C[edge=4q+r][h=nt*16+t] ---
    f32x4 accM[4];
    #pragma unroll
    for (int nt = 0; nt < 4; ++nt) {
      f32x4 c = {0.f, 0.f, 0.f, 0.f};
      c = MFMA(af4, *reinterpret_cast<const bf16x8*>(&WoLoT[(nt * 16 + t) * 72 + q * 8]), c);
      c = MFMA(af5, *reinterpret_cast<const bf16x8*>(&WoLoT[(nt * 16 + t) * 72 + 32 + q * 8]), c);
      #pragma unroll
      for (int r = 0; r < 4; ++r)
        c[r] = fmaxf(c[r] + bf2f(yv[r * 4 + nt]) + boL[nt], 0.f);
      accM[nt] = c;
    }
    sync_wave();  // E reads drained before next iteration's writes

    // --- issue next iteration's y gather (yv regs now free) ---
    #pragma unroll
    for (int r = 0; r < 4; ++r) {
      const int idx = 16 * itn + 4 * q + r;
      const int sn = (itn < 4) ? __shfl(si0, idx) : __shfl(si1, idx - 64);
      const unsigned short* yp = y + (long)sn * 64 + t;
      #pragma unroll
      for (int nt = 0; nt < 4; ++nt) yv[r * 4 + nt] = yp[nt * 16];
    }

    // --- sparsemax over 16 logits (count-based, exact incl. ties) ---
    const float z = a;
    float cp = 0.f, sp = 0.f;  // partials over j in {4q..4q+3}
    #pragma unroll
    for (int r = 0; r < 4; ++r) {
      float zj = __shfl(z, 4 * q + r, 16);
      const bool ge = (zj >= z);
      cp += ge ? 1.f : 0.f;
      sp += ge ? zj : 0.f;
    }
    cp += __shfl_xor(cp, 16); sp += __shfl_xor(sp, 16);
    cp += __shfl_xor(cp, 32); sp += __shfl_xor(sp, 32);
    const bool valid = 1.f + cp * z > sp;
    float kf = valid ? cp : 0.f;
    float sv = valid ? sp : 0.f;
    #pragma unroll
    for (int m = 1; m < 16; m <<= 1) {
      float ok = __shfl_xor(kf, m), os = __shfl_xor(sv, m);
      if (ok > kf) { kf = ok; sv = os; }
    }
    const float tau = (sv - 1.f) / kf;
    const float alpha = fmaxf(a - tau, 0.f);  // own edge t

    // --- h_neigh = alpha^T . m ---
    float al[4];
    #pragma unroll
    for (int r = 0; r < 4; ++r) al[r] = __shfl(alpha, 4 * q + r);
    float p[4];
    #pragma unroll
    for (int nt = 0; nt < 4; ++nt) {
      p[nt] = al[0] * accM[nt][0] + al[1] * accM[nt][1] +
              al[2] * accM[nt][2] + al[3] * accM[nt][3];
      p[nt] += __shfl_xor(p[nt], 16);
      p[nt] += __shfl_xor(p[nt], 32);
    }
    const float pown = (q == 0) ? p[0] : (q == 1) ? p[1] : (q == 2) ? p[2] : p[3];
    hn_out[(long)n * 64 + lane] = pown;  // coalesced 256B/wave
  }
}

// ---------- Fallback edge kernel (round-3 verbatim, needs no workspace y) ----------
extern "C" __global__ void __launch_bounds__(256, 3)
gteast_edge_fb(const float* __restrict__ nf, const float* __restrict__ ef,
               const int* __restrict__ src_idx,
               const float* __restrict__ We, const float* __restrict__ be,
               const float* __restrict__ Wo, const float* __restrict__ bo,
               const float* __restrict__ vc,
               float* __restrict__ hn_out) {
  __shared__ unsigned short WeT[64 * 72];
  __shared__ unsigned short WoT[64 * 200];
  __shared__ unsigned short Elds[4][16 * 72];
  __shared__ float vls[68];

  const int tid = threadIdx.x;
  for (int i = tid; i < 64 * 64; i += 256) {
    int k = i >> 6, n = i & 63;
    WeT[n * 72 + k] = f2bf(We[i]);
  }
  for (int i = tid; i < 192 * 64; i += 256) {
    int k = i >> 6, n = i & 63;
    WoT[n * 200 + k] = f2bf(Wo[i]);
  }
  if (tid < 65) vls[tid] = vc[tid];
  __syncthreads();

  const int lane = tid & 63, w = tid >> 6;
  const int q = lane >> 4, t = lane & 15;
  const int wid = blockIdx.x * 4 + w;
  if (wid * 8 >= ND) return;

  unsigned short* E = Elds[w];
  const float cval = vls[64];
  float beL[4], boL[4];
  #pragma unroll
  for (int nt = 0; nt < 4; ++nt) { beL[nt] = be[nt * 16 + t]; boL[nt] = bo[nt * 16 + t]; }
  float vsl[16];
  #pragma unroll
  for (int j = 0; j < 8; ++j) { vsl[j] = vls[q * 8 + j]; vsl[8 + j] = vls[32 + q * 8 + j]; }

  const int si0 = src_idx[wid * 128 + lane];
  const int si1 = src_idx[wid * 128 + 64 + lane];
  const long ebase = (long)(wid * 128);

  float4 efn[4];
  {
    const float* er = ef + (ebase + t) * 64 + q * 8;
    efn[0] = *reinterpret_cast<const float4*>(er);
    efn[1] = *reinterpret_cast<const float4*>(er + 4);
    efn[2] = *reinterpret_cast<const float4*>(er + 32);
    efn[3] = *reinterpret_cast<const float4*>(er + 36);
  }
  float hraw[32];
  {
    const int s0 = __shfl(si0, t);
    const float* hp = nf + (long)s0 * 128 + q * 8;
    #pragma unroll
    for (int kc = 0; kc < 4; ++kc) {
      float4 a0 = *reinterpret_cast<const float4*>(hp + kc * 32);
      float4 a1 = *reinterpret_cast<const float4*>(hp + kc * 32 + 4);
      hraw[kc * 8 + 0] = a0.x; hraw[kc * 8 + 1] = a0.y; hraw[kc * 8 + 2] = a0.z; hraw[kc * 8 + 3] = a0.w;
      hraw[kc * 8 + 4] = a1.x; hraw[kc * 8 + 5] = a1.y; hraw[kc * 8 + 6] = a1.z; hraw[kc * 8 + 7] = a1.w;
    }
  }

  for (int it = 0; it < 8; ++it) {
    const int n = wid * 8 + it;
    const int itn = it < 7 ? it + 1 : 7;

    float fe[16];
    fe[0] = efn[0].x; fe[1] = efn[0].y; fe[2] = efn[0].z; fe[3] = efn[0].w;
    fe[4] = efn[1].x; fe[5] = efn[1].y; fe[6] = efn[1].z; fe[7] = efn[1].w;
    fe[8] = efn[2].x; fe[9] = efn[2].y; fe[10] = efn[2].z; fe[11] = efn[2].w;
    fe[12] = efn[3].x; fe[13] = efn[3].y; fe[14] = efn[3].z; fe[15] = efn[3].w;
    {
      const float* er = ef + (ebase + itn * 16 + t) * 64 + q * 8;
      efn[0] = *reinterpret_cast<const float4*>(er);
      efn[1] = *reinterpret_cast<const float4*>(er + 4);
      efn[2] = *reinterpret_cast<const float4*>(er + 32);
      efn[3] = *reinterpret_cast<const float4*>(er + 36);
    }

    float ap = 0.f;
    #pragma unroll
    for (int j = 0; j < 16; ++j) ap += fe[j] * vsl[j];
    ap += __shfl_xor(ap, 16);
    ap += __shfl_xor(ap, 32);
    float a = ap + cval;
    a = a > 0.f ? a : 0.01f * a;

    const bf16x8 e0 = pack8(fe), e1 = pack8(fe + 8);
    #pragma unroll
    for (int nt = 0; nt < 4; ++nt) {
      f32x4 c = {0.f, 0.f, 0.f, 0.f};
      c = MFMA(e0, *reinterpret_cast<const bf16x8*>(&WeT[(nt * 16 + t) * 72 + q * 8]), c);
      c = MFMA(e1, *reinterpret_cast<const bf16x8*>(&WeT[(nt * 16 + t) * 72 + 32 + q * 8]), c);
      #pragma unroll
      for (int r = 0; r < 4; ++r) {
        float vv = fmaxf(c[r] + beL[nt], 0.f);
        E[(4 * q + r) * 72 + nt * 16 + t] = f2bf(vv);
      }
    }
    sync_wave();

    bf16x8 af[6];
    #pragma unroll
    for (int kc = 0; kc < 4; ++kc) af[kc] = pack8(hraw + kc * 8);
    af[4] = *reinterpret_cast<const bf16x8*>(&E[t * 72 + q * 8]);
    af[5] = *reinterpret_cast<const bf16x8*>(&E[t * 72 + 32 + q * 8]);

    {
      const int sn = (itn < 4) ? __shfl(si0, 16 * itn + t)
                               : __shfl(si1, 16 * (itn - 4) + t);
      const float* hp = nf + (long)sn * 128 + q * 8;
      #pragma unroll
      for (int kc = 0; kc < 4; ++kc) {
        float4 a0 = *reinterpret_cast<const float4*>(hp + kc * 32);
        float4 a1 = *reinterpret_cast<const float4*>(hp + kc * 32 + 4);
        hraw[kc * 8 + 0] = a0.x; hraw[kc * 8 + 1] = a0.y; hraw[kc * 8 + 2] = a0.z; hraw[kc * 8 + 3] = a0.w;
        hraw[kc * 8 + 4] = a1.x; hraw[kc * 8 + 5] = a1.y; hraw[kc * 8 + 6] = a1.z; hraw[kc * 8 + 7] = a1.w;
      }
    }

    f32x4 accM[4];
    #pragma unroll
    for (int nt = 0; nt < 4; ++nt) {
      f32x4 c = {0.f, 0.f, 0.f, 0.f};
      #pragma unroll
      for (int kc = 0; kc < 6; ++kc)
        c = MFMA(af[kc], *reinterpret_cast<const bf16x8*>(&WoT[(nt * 16 + t) * 200 + kc * 32 + q * 8]), c);
      #pragma unroll
      for (int r = 0; r < 4; ++r) c[r] = fmaxf(c[r] + boL[nt], 0.f);
      accM[nt] = c;
    }
    sync_wave();

    float zz = a;
    #pragma unroll
    for (int k = 2; k <= 16; k <<= 1) {
      #pragma unroll
      for (int j = k >> 1; j > 0; j >>= 1) {
        float o = __shfl_xor(zz, j);
        const bool upper = (t & j) != 0;
        const bool desc = (t & k) == 0;
        zz = (upper != desc) ? fmaxf(zz, o) : fminf(zz, o);
      }
    }
    float cs = zz;
    #pragma unroll
    for (int off = 1; off < 16; off <<= 1) {
      float o = __shfl_up(cs, off, 16);
      cs += (t >= off) ? o : 0.f;
    }
    const bool gt = 1.f + (float)(t + 1) * zz > cs;
    float kf = gt ? (float)(t + 1) : 0.f;
    float sv = gt ? zz : 0.f;
    #pragma unroll
    for (int m = 1; m < 16; m <<= 1) {
      kf = fmaxf(kf, __shfl_xor(kf, m));
      sv += __shfl_xor(sv, m);
    }
    const float tau = (sv - 1.f) / kf;
    const float alpha = fmaxf(a - tau, 0.f);

    float al[4];
    #pragma unroll
    for (int r = 0; r < 4; ++r) al[r] = __shfl(alpha, 4 * q + r);
    float p[4];
    #pragma unroll
    for (int nt = 0; nt < 4; ++nt) {
      p[nt] = al[0] * accM[nt][0] + al[1] * accM[nt][1] +
              al[2] * accM[nt][2] + al[3] * accM[nt][3];
      p[nt] += __shfl_xor(p[nt], 16);
      p[nt] += __shfl_xor(p[nt], 32);
    }
    const float pown = (q == 0) ? p[0] : (q == 1) ? p[1] : (q == 2) ? p[2] : p[3];
    hn_out[(long)n * 64 + lane] = pown;
  }
}

// ---------- K2: out = relu([h_dst | h_neigh] @ Wn + bn), in place ----------
extern "C" __global__ void __launch_bounds__(256, 3)
gteast_out(const float* __restrict__ nf, const float* __restrict__ Wn,
           const float* __restrict__ bn, float* __restrict__ out) {
  __shared__ unsigned short WnT[64 * 200];
  const int tid = threadIdx.x;
  for (int i = tid; i < 192 * 64; i += 256) {
    int k = i >> 6, nn = i & 63;
    WnT[nn * 200 + k] = f2bf(Wn[i]);
  }
  __syncthreads();

  const int lane = tid & 63, w = tid >> 6, q = lane >> 4, t = lane & 15;
  const int tile = blockIdx.x * 4 + w;
  if (tile >= ND / 16) return;
  const int r0 = tile * 16;

  float bnL[4];
  #pragma unroll
  for (int nt = 0; nt < 4; ++nt) bnL[nt] = bn[nt * 16 + t];

  float raw[8];
  bf16x8 af[6];
  const float* hp = nf + (long)(r0 + t) * 128 + q * 8;
  #pragma unroll
  for (int kc = 0; kc < 4; ++kc) {
    float4 a0 = *reinterpret_cast<const float4*>(hp + kc * 32);
    float4 a1 = *reinterpret_cast<const float4*>(hp + kc * 32 + 4);
    raw[0] = a0.x; raw[1] = a0.y; raw[2] = a0.z; raw[3] = a0.w;
    raw[4] = a1.x; raw[5] = a1.y; raw[6] = a1.z; raw[7] = a1.w;
    af[kc] = pack8(raw);
  }
  const float* gp = out + (long)(r0 + t) * 64 + q * 8;
  #pragma unroll
  for (int kc = 0; kc < 2; ++kc) {
    float4 a0 = *reinterpret_cast<const float4*>(gp + kc * 32);
    float4 a1 = *reinterpret_cast<const float4*>(gp + kc * 32 + 4);
    raw[0] = a0.x; raw[1] = a0.y; raw[2] = a0.z; raw[3] = a0.w;
    raw[4] = a1.x; raw[5] = a1.y; raw[6] = a1.z; raw[7] = a1.w;
    af[4 + kc] = pack8(raw);
  }

  #pragma unroll
  for (int nt = 0; nt < 4; ++nt) {
    f32x4 c = {0.f, 0.f, 0.f, 0.f};
    #pragma unroll
    for (int kc = 0; kc < 6; ++kc)
      c = MFMA(af[kc], *reinterpret_cast<const bf16x8*>(&WnT[(nt * 16 + t) * 200 + kc * 32 + q * 8]), c);
    #pragma unroll
    for (int r = 0; r < 4; ++r)
      out[(long)(r0 + 4 * q + r) * 64 + nt * 16 + t] = fmaxf(c[r] + bnL[nt], 0.f);
  }
}

extern "C" void kernel_launch(void* const* d_in, const int* in_sizes, int n_in,
                              void* d_out, int out_size, void* d_ws, size_t ws_size,
                              hipStream_t stream) {
  const float* nf = (const float*)d_in[0];
  const float* ef = (const float*)d_in[1];
  const int* si   = (const int*)d_in[2];
  const float* We = (const float*)d_in[3];
  const float* be = (const float*)d_in[4];
  const float* Wa = (const float*)d_in[5];
  const float* ba = (const float*)d_in[6];
  const float* wa = (const float*)d_in[7];
  const float* Wo = (const float*)d_in[8];
  const float* bo = (const float*)d_in[9];
  const float* Wn = (const float*)d_in[10];
  const float* bn = (const float*)d_in[11];
  float* out = (float*)d_out;
  float* vc = (float*)d_ws;  // 65 floats at ws[0]

  const size_t yneed = 512 + (size_t)NS * 64 * sizeof(unsigned short);

  gteast_prep<<<1, 256, 0, stream>>>(Wa, ba, wa, vc);
  if (ws_size >= yneed) {
    unsigned short* y = (unsigned short*)((char*)d_ws + 512);
    gteast_src<<<1563, 256, 0, stream>>>(nf, Wo, y);
    gteast_edge<<<1563, 256, 0, stream>>>(ef, si, We, be, Wo, bo, vc, y, out);
  } else {
    gteast_edge_fb<<<1563, 256, 0, stream>>>(nf, ef, si, We, be, Wo, bo, vc, out);
  }
  gteast_out<<<782, 256, 0, stream>>>(nf, Wn, bn, out);
}

// Round 5
// 370.025 us; speedup vs baseline: 1.7728x; 1.0094x over previous
//
#include <hip/hip_runtime.h>

// GTEAST layer, round 8: frag-packed y + z-fold + slim out kernel.
//   y = nf@Wo_up  (100000x64 bf16, frag-packed y2[s][t*4+nt], 12.8MB ws)
//   z = nf@Wn_up  (50000x64 bf16, same packing, 6.4MB ws) -- computed in
//       gteast_src from the SAME nf registers (no extra HBM reads).
//   edge: m = relu(y[src] + e_out@Wo_lo + bo); y gather = 4x 8B loads/lane
//         (was 16x 2B scalar).
//   out:  out = relu(z[dst] + h_neigh@Wn_lo + bn); no nf re-read (25.6MB
//         saved), 24->8 MFMA/tile, LDS 18.6K->9.2K.
// Lessons kept: NO invariant-frag hoisting / NO operand-swap e-GEMM (rounds
// 4-6 all spilled); Elds round-trip retained (splits live ranges, ~80 VGPR);
// count-based sparsemax (exact incl. ties). Fallback path if ws too small.

#define ND 50000
#define NS 100000

typedef __bf16 bf16x8 __attribute__((ext_vector_type(8)));
typedef float f32x4 __attribute__((ext_vector_type(4)));
typedef unsigned short u16x4 __attribute__((ext_vector_type(4)));

__device__ __forceinline__ void sync_wave() {
  asm volatile("s_waitcnt lgkmcnt(0)" ::: "memory");
}

// fp32 -> bf16 RNE
__device__ __forceinline__ unsigned short f2bf(float x) {
  unsigned u = __float_as_uint(x);
  u += 0x7fffu + ((u >> 16) & 1u);
  return (unsigned short)(u >> 16);
}
__device__ __forceinline__ float bf2f(unsigned short u) {
  return __uint_as_float((unsigned)u << 16);
}

union Frag8 { bf16x8 v; unsigned u32[4]; };

// 8 floats -> bf16x8, round-half-up (+0x8000) + v_perm pack
__device__ __forceinline__ bf16x8 pack8(const float* fr) {
  Frag8 f;
  #pragma unroll
  for (int j = 0; j < 4; ++j) {
    unsigned lo = __float_as_uint(fr[2 * j]) + 0x8000u;
    unsigned hi = __float_as_uint(fr[2 * j + 1]) + 0x8000u;
    f.u32[j] = __builtin_amdgcn_perm(hi, lo, 0x07060302);
  }
  return f.v;
}

#define MFMA(a, b, c) __builtin_amdgcn_mfma_f32_16x16x32_bf16((a), (b), (c), 0, 0, 0)

// ---------- K0: v = Wa@wa, c = ba.wa ----------
extern "C" __global__ void gteast_prep(const float* __restrict__ Wa,
                                       const float* __restrict__ ba,
                                       const float* __restrict__ wa,
                                       float* __restrict__ vc) {
  __shared__ float red[260];
  const int tid = threadIdx.x, k = tid >> 2, p = tid & 3;
  float s = 0.f;
  for (int h = 16 * p; h < 16 * p + 16; ++h) s += Wa[k * 64 + h] * wa[h];
  red[tid] = s;
  if (tid < 4) {
    float sc = 0.f;
    for (int h = 16 * tid; h < 16 * tid + 16; ++h) sc += ba[h] * wa[h];
    red[256 + tid] = sc;
  }
  __syncthreads();
  if (p == 0) vc[k] = red[4 * k] + red[4 * k + 1] + red[4 * k + 2] + red[4 * k + 3];
  if (tid == 0) vc[64] = red[256] + red[257] + red[258] + red[259];
}

// ---------- K_y: y = nf@Wo_up (all NS rows), z = nf@Wn_up (first ND rows) ----
// Both stored bf16 FRAG-PACKED: buf[row*64 + t*4 + nt] = val[row][h=nt*16+t],
// so consumers read one 8B u16x4 per row instead of 4 stride-32B scalars.
extern "C" __global__ void __launch_bounds__(256, 3)
gteast_src(const float* __restrict__ nf, const float* __restrict__ Wo,
           const float* __restrict__ Wn,
           unsigned short* __restrict__ y, unsigned short* __restrict__ z) {
  __shared__ unsigned short WuT[64 * 136];   // Wo_up^T[h][k], stride 136
  __shared__ unsigned short WnuT[64 * 136];  // Wn_up^T[h][k]
  const int tid = threadIdx.x;
  for (int i = tid; i < 128 * 64; i += 256) {
    int k = i >> 6, n = i & 63;
    WuT[n * 136 + k] = f2bf(Wo[i]);
    WnuT[n * 136 + k] = f2bf(Wn[i]);
  }
  __syncthreads();

  const int lane = tid & 63, w = tid >> 6, q = lane >> 4, t = lane & 15;
  const int tile = blockIdx.x * 4 + w;  // 6250 active
  if (tile >= NS / 16) return;
  const int r0 = tile * 16;

  float raw[8];
  bf16x8 af[4];
  const float* hp = nf + (long)(r0 + t) * 128 + q * 8;
  #pragma unroll
  for (int kc = 0; kc < 4; ++kc) {
    float4 a0 = *reinterpret_cast<const float4*>(hp + kc * 32);
    float4 a1 = *reinterpret_cast<const float4*>(hp + kc * 32 + 4);
    raw[0] = a0.x; raw[1] = a0.y; raw[2] = a0.z; raw[3] = a0.w;
    raw[4] = a1.x; raw[5] = a1.y; raw[6] = a1.z; raw[7] = a1.w;
    af[kc] = pack8(raw);
  }

  f32x4 accY[4];
  #pragma unroll
  for (int nt = 0; nt < 4; ++nt) {
    f32x4 c = {0.f, 0.f, 0.f, 0.f};
    #pragma unroll
    for (int kc = 0; kc < 4; ++kc)
      c = MFMA(af[kc], *reinterpret_cast<const bf16x8*>(&WuT[(nt * 16 + t) * 136 + kc * 32 + q * 8]), c);
    accY[nt] = c;
  }
  #pragma unroll
  for (int r = 0; r < 4; ++r) {
    u16x4 v = {f2bf(accY[0][r]), f2bf(accY[1][r]), f2bf(accY[2][r]), f2bf(accY[3][r])};
    *reinterpret_cast<u16x4*>(y + (long)(r0 + 4 * q + r) * 64 + t * 4) = v;
  }

  if (tile < ND / 16) {  // z for dst rows only
    f32x4 accZ[4];
    #pragma unroll
    for (int nt = 0; nt < 4; ++nt) {
      f32x4 c = {0.f, 0.f, 0.f, 0.f};
      #pragma unroll
      for (int kc = 0; kc < 4; ++kc)
        c = MFMA(af[kc], *reinterpret_cast<const bf16x8*>(&WnuT[(nt * 16 + t) * 136 + kc * 32 + q * 8]), c);
      accZ[nt] = c;
    }
    #pragma unroll
    for (int r = 0; r < 4; ++r) {
      u16x4 v = {f2bf(accZ[0][r]), f2bf(accZ[1][r]), f2bf(accZ[2][r]), f2bf(accZ[3][r])};
      *reinterpret_cast<u16x4*>(z + (long)(r0 + 4 * q + r) * 64 + t * 4) = v;
    }
  }
}

// ---------- K1: fused e_out + attention + m + sparsemax + h_neigh ----------
extern "C" __global__ void __launch_bounds__(256, 3)
gteast_edge(const float* __restrict__ ef, const int* __restrict__ src_idx,
            const float* __restrict__ We, const float* __restrict__ be,
            const float* __restrict__ Wo, const float* __restrict__ bo,
            const float* __restrict__ vc, const unsigned short* __restrict__ y,
            float* __restrict__ hn_out) {
  __shared__ unsigned short WeT[64 * 72];      // We^T[n][k]
  __shared__ unsigned short WoLoT[64 * 72];    // Wo^T rows 128..191 (e_out part)
  __shared__ unsigned short Elds[4][16 * 72];  // per-wave e_out tile [m][h]
  __shared__ float vls[68];                    // v[64], c at [64]

  const int tid = threadIdx.x;
  for (int i = tid; i < 64 * 64; i += 256) {
    int k = i >> 6, n = i & 63;
    WeT[n * 72 + k] = f2bf(We[i]);
  }
  for (int i = tid; i < 64 * 64; i += 256) {
    int k = i >> 6, n = i & 63;
    WoLoT[n * 72 + k] = f2bf(Wo[(128 + k) * 64 + n]);
  }
  if (tid < 65) vls[tid] = vc[tid];
  __syncthreads();

  const int lane = tid & 63, w = tid >> 6;
  const int q = lane >> 4, t = lane & 15;
  const int wid = blockIdx.x * 4 + w;  // 6250 active
  if (wid * 8 >= ND) return;           // after the only __syncthreads

  unsigned short* E = Elds[w];
  const float cval = vls[64];
  float beL[4], boL[4];
  #pragma unroll
  for (int nt = 0; nt < 4; ++nt) { beL[nt] = be[nt * 16 + t]; boL[nt] = bo[nt * 16 + t]; }
  float vsl[16];
  #pragma unroll
  for (int j = 0; j < 8; ++j) { vsl[j] = vls[q * 8 + j]; vsl[8 + j] = vls[32 + q * 8 + j]; }

  const int si0 = src_idx[wid * 128 + lane];
  const int si1 = src_idx[wid * 128 + 64 + lane];

  const long ebase = (long)(wid * 128);

  // --- prologue: prefetch ef(0) and y(0) ---
  float4 efn[4];
  {
    const float* er = ef + (ebase + t) * 64 + q * 8;
    efn[0] = *reinterpret_cast<const float4*>(er);
    efn[1] = *reinterpret_cast<const float4*>(er + 4);
    efn[2] = *reinterpret_cast<const float4*>(er + 32);
    efn[3] = *reinterpret_cast<const float4*>(er + 36);
  }
  u16x4 yv[4];  // yv[r][nt] = y[src(edge 4q+r)][h=nt*16+t]
  #pragma unroll
  for (int r = 0; r < 4; ++r) {
    const int s0 = __shfl(si0, 4 * q + r);
    yv[r] = *reinterpret_cast<const u16x4*>(y + (long)s0 * 64 + t * 4);
  }

  for (int it = 0; it < 8; ++it) {
    const int n = wid * 8 + it;
    const int itn = it < 7 ? it + 1 : 7;

    // --- snapshot current ef, issue next ef loads ---
    float fe[16];
    fe[0] = efn[0].x; fe[1] = efn[0].y; fe[2] = efn[0].z; fe[3] = efn[0].w;
    fe[4] = efn[1].x; fe[5] = efn[1].y; fe[6] = efn[1].z; fe[7] = efn[1].w;
    fe[8] = efn[2].x; fe[9] = efn[2].y; fe[10] = efn[2].z; fe[11] = efn[2].w;
    fe[12] = efn[3].x; fe[13] = efn[3].y; fe[14] = efn[3].z; fe[15] = efn[3].w;
    {
      const float* er = ef + (ebase + itn * 16 + t) * 64 + q * 8;
      efn[0] = *reinterpret_cast<const float4*>(er);
      efn[1] = *reinterpret_cast<const float4*>(er + 4);
      efn[2] = *reinterpret_cast<const float4*>(er + 32);
      efn[3] = *reinterpret_cast<const float4*>(er + 36);
    }

    // --- fp32 attention logit (exact) ---
    float ap = 0.f;
    #pragma unroll
    for (int j = 0; j < 16; ++j) ap += fe[j] * vsl[j];
    ap += __shfl_xor(ap, 16);
    ap += __shfl_xor(ap, 32);
    float a = ap + cval;
    a = a > 0.f ? a : 0.01f * a;  // leaky_relu

    // --- e GEMM: e_out = relu(ef @ We + be) ---
    const bf16x8 e0 = pack8(fe), e1 = pack8(fe + 8);
    #pragma unroll
    for (int nt = 0; nt < 4; ++nt) {
      f32x4 c = {0.f, 0.f, 0.f, 0.f};
      c = MFMA(e0, *reinterpret_cast<const bf16x8*>(&WeT[(nt * 16 + t) * 72 + q * 8]), c);
      c = MFMA(e1, *reinterpret_cast<const bf16x8*>(&WeT[(nt * 16 + t) * 72 + 32 + q * 8]), c);
      #pragma unroll
      for (int r = 0; r < 4; ++r) {
        float vv = fmaxf(c[r] + beL[nt], 0.f);
        E[(4 * q + r) * 72 + nt * 16 + t] = f2bf(vv);
      }
    }
    sync_wave();

    // --- e_out A-frags from E ---
    bf16x8 af4 = *reinterpret_cast<const bf16x8*>(&E[t * 72 + q * 8]);
    bf16x8 af5 = *reinterpret_cast<const bf16x8*>(&E[t * 72 + 32 + q * 8]);

    // --- m GEMM: m = relu(y[src] + e_out @ Wo_lo + bo), C[edge=4q+r][h=nt*16+t] ---
    f32x4 accM[4];
    #pragma unroll
    for (int nt = 0; nt < 4; ++nt) {
      f32x4 c = {0.f, 0.f, 0.f, 0.f};
      c = MFMA(af4, *reinterpret_cast<const bf16x8*>(&WoLoT[(nt * 16 + t) * 72 + q * 8]), c);
      c = MFMA(af5, *reinterpret_cast<const bf16x8*>(&WoLoT[(nt * 16 + t) * 72 + 32 + q * 8]), c);
      #pragma unroll
      for (int r = 0; r < 4; ++r)
        c[r] = fmaxf(c[r] + bf2f(yv[r][nt]) + boL[nt], 0.f);
      accM[nt] = c;
    }
    sync_wave();  // E reads drained before next iteration's writes

    // --- issue next iteration's y gather (yv regs now free) ---
    #pragma unroll
    for (int r = 0; r < 4; ++r) {
      const int idx = 16 * itn + 4 * q + r;
      const int sn = (idx < 64) ? __shfl(si0, idx) : __shfl(si1, idx - 64);
      yv[r] = *reinterpret_cast<const u16x4*>(y + (long)sn * 64 + t * 4);
    }

    // --- sparsemax over 16 logits (count-based, exact incl. ties) ---
    const float z = a;
    float cp = 0.f, sp = 0.f;  // partials over j in {4q..4q+3}
    #pragma unroll
    for (int r = 0; r < 4; ++r) {
      float zj = __shfl(z, 4 * q + r, 16);
      const bool ge = (zj >= z);
      cp += ge ? 1.f : 0.f;
      sp += ge ? zj : 0.f;
    }
    cp += __shfl_xor(cp, 16); sp += __shfl_xor(sp, 16);
    cp += __shfl_xor(cp, 32); sp += __shfl_xor(sp, 32);
    const bool valid = 1.f + cp * z > sp;
    float kf = valid ? cp : 0.f;
    float sv = valid ? sp : 0.f;
    #pragma unroll
    for (int m = 1; m < 16; m <<= 1) {
      float ok = __shfl_xor(kf, m), os = __shfl_xor(sv, m);
      if (ok > kf) { kf = ok; sv = os; }
    }
    const float tau = (sv - 1.f) / kf;
    const float alpha = fmaxf(a - tau, 0.f);  // own edge t

    // --- h_neigh = alpha^T . m ---
    float al[4];
    #pragma unroll
    for (int r = 0; r < 4; ++r) al[r] = __shfl(alpha, 4 * q + r);
    float p[4];
    #pragma unroll
    for (int nt = 0; nt < 4; ++nt) {
      p[nt] = al[0] * accM[nt][0] + al[1] * accM[nt][1] +
              al[2] * accM[nt][2] + al[3] * accM[nt][3];
      p[nt] += __shfl_xor(p[nt], 16);
      p[nt] += __shfl_xor(p[nt], 32);
    }
    const float pown = (q == 0) ? p[0] : (q == 1) ? p[1] : (q == 2) ? p[2] : p[3];
    hn_out[(long)n * 64 + lane] = pown;  // coalesced 256B/wave
  }
}

// ---------- K2: out = relu(z[dst] + h_neigh @ Wn_lo + bn), in place ----------
extern "C" __global__ void __launch_bounds__(256, 4)
gteast_out(const unsigned short* __restrict__ z, const float* __restrict__ Wn,
           const float* __restrict__ bn, float* __restrict__ out) {
  __shared__ unsigned short WnLoT[64 * 72];  // Wn^T rows 128..191
  const int tid = threadIdx.x;
  for (int i = tid; i < 64 * 64; i += 256) {
    int k = i >> 6, nn = i & 63;
    WnLoT[nn * 72 + k] = f2bf(Wn[(128 + k) * 64 + nn]);
  }
  __syncthreads();

  const int lane = tid & 63, w = tid >> 6, q = lane >> 4, t = lane & 15;
  const int tile = blockIdx.x * 4 + w;  // 3125 active
  if (tile >= ND / 16) return;
  const int r0 = tile * 16;

  float bnL[4];
  #pragma unroll
  for (int nt = 0; nt < 4; ++nt) bnL[nt] = bn[nt * 16 + t];

  // h_neigh A-frags (staged fp32 by K1 in `out`)
  float raw[8];
  bf16x8 af4, af5;
  const float* gp = out + (long)(r0 + t) * 64 + q * 8;
  {
    float4 a0 = *reinterpret_cast<const float4*>(gp);
    float4 a1 = *reinterpret_cast<const float4*>(gp + 4);
    raw[0] = a0.x; raw[1] = a0.y; raw[2] = a0.z; raw[3] = a0.w;
    raw[4] = a1.x; raw[5] = a1.y; raw[6] = a1.z; raw[7] = a1.w;
    af4 = pack8(raw);
    a0 = *reinterpret_cast<const float4*>(gp + 32);
    a1 = *reinterpret_cast<const float4*>(gp + 36);
    raw[0] = a0.x; raw[1] = a0.y; raw[2] = a0.z; raw[3] = a0.w;
    raw[4] = a1.x; raw[5] = a1.y; raw[6] = a1.z; raw[7] = a1.w;
    af5 = pack8(raw);
  }
  // z gather (frag-packed, one 8B load per row)
  u16x4 zv[4];
  #pragma unroll
  for (int r = 0; r < 4; ++r)
    zv[r] = *reinterpret_cast<const u16x4*>(z + (long)(r0 + 4 * q + r) * 64 + t * 4);

  #pragma unroll
  for (int nt = 0; nt < 4; ++nt) {
    f32x4 c = {0.f, 0.f, 0.f, 0.f};
    c = MFMA(af4, *reinterpret_cast<const bf16x8*>(&WnLoT[(nt * 16 + t) * 72 + q * 8]), c);
    c = MFMA(af5, *reinterpret_cast<const bf16x8*>(&WnLoT[(nt * 16 + t) * 72 + 32 + q * 8]), c);
    #pragma unroll
    for (int r = 0; r < 4; ++r)
      out[(long)(r0 + 4 * q + r) * 64 + nt * 16 + t] =
          fmaxf(c[r] + bf2f(zv[r][nt]) + bnL[nt], 0.f);
  }
}

// ---------- Fallback edge kernel (round-3 verbatim, no workspace) ----------
extern "C" __global__ void __launch_bounds__(256, 3)
gteast_edge_fb(const float* __restrict__ nf, const float* __restrict__ ef,
               const int* __restrict__ src_idx,
               const float* __restrict__ We, const float* __restrict__ be,
               const float* __restrict__ Wo, const float* __restrict__ bo,
               const float* __restrict__ vc,
               float* __restrict__ hn_out) {
  __shared__ unsigned short WeT[64 * 72];
  __shared__ unsigned short WoT[64 * 200];
  __shared__ unsigned short Elds[4][16 * 72];
  __shared__ float vls[68];

  const int tid = threadIdx.x;
  for (int i = tid; i < 64 * 64; i += 256) {
    int k = i >> 6, n = i & 63;
    WeT[n * 72 + k] = f2bf(We[i]);
  }
  for (int i = tid; i < 192 * 64; i += 256) {
    int k = i >> 6, n = i & 63;
    WoT[n * 200 + k] = f2bf(Wo[i]);
  }
  if (tid < 65) vls[tid] = vc[tid];
  __syncthreads();

  const int lane = tid & 63, w = tid >> 6;
  const int q = lane >> 4, t = lane & 15;
  const int wid = blockIdx.x * 4 + w;
  if (wid * 8 >= ND) return;

  unsigned short* E = Elds[w];
  const float cval = vls[64];
  float beL[4], boL[4];
  #pragma unroll
  for (int nt = 0; nt < 4; ++nt) { beL[nt] = be[nt * 16 + t]; boL[nt] = bo[nt * 16 + t]; }
  float vsl[16];
  #pragma unroll
  for (int j = 0; j < 8; ++j) { vsl[j] = vls[q * 8 + j]; vsl[8 + j] = vls[32 + q * 8 + j]; }

  const int si0 = src_idx[wid * 128 + lane];
  const int si1 = src_idx[wid * 128 + 64 + lane];
  const long ebase = (long)(wid * 128);

  float4 efn[4];
  {
    const float* er = ef + (ebase + t) * 64 + q * 8;
    efn[0] = *reinterpret_cast<const float4*>(er);
    efn[1] = *reinterpret_cast<const float4*>(er + 4);
    efn[2] = *reinterpret_cast<const float4*>(er + 32);
    efn[3] = *reinterpret_cast<const float4*>(er + 36);
  }
  float hraw[32];
  {
    const int s0 = __shfl(si0, t);
    const float* hp = nf + (long)s0 * 128 + q * 8;
    #pragma unroll
    for (int kc = 0; kc < 4; ++kc) {
      float4 a0 = *reinterpret_cast<const float4*>(hp + kc * 32);
      float4 a1 = *reinterpret_cast<const float4*>(hp + kc * 32 + 4);
      hraw[kc * 8 + 0] = a0.x; hraw[kc * 8 + 1] = a0.y; hraw[kc * 8 + 2] = a0.z; hraw[kc * 8 + 3] = a0.w;
      hraw[kc * 8 + 4] = a1.x; hraw[kc * 8 + 5] = a1.y; hraw[kc * 8 + 6] = a1.z; hraw[kc * 8 + 7] = a1.w;
    }
  }

  for (int it = 0; it < 8; ++it) {
    const int n = wid * 8 + it;
    const int itn = it < 7 ? it + 1 : 7;

    float fe[16];
    fe[0] = efn[0].x; fe[1] = efn[0].y; fe[2] = efn[0].z; fe[3] = efn[0].w;
    fe[4] = efn[1].x; fe[5] = efn[1].y; fe[6] = efn[1].z; fe[7] = efn[1].w;
    fe[8] = efn[2].x; fe[9] = efn[2].y; fe[10] = efn[2].z; fe[11] = efn[2].w;
    fe[12] = efn[3].x; fe[13] = efn[3].y; fe[14] = efn[3].z; fe[15] = efn[3].w;
    {
      const float* er = ef + (ebase + itn * 16 + t) * 64 + q * 8;
      efn[0] = *reinterpret_cast<const float4*>(er);
      efn[1] = *reinterpret_cast<const float4*>(er + 4);
      efn[2] = *reinterpret_cast<const float4*>(er + 32);
      efn[3] = *reinterpret_cast<const float4*>(er + 36);
    }

    float ap = 0.f;
    #pragma unroll
    for (int j = 0; j < 16; ++j) ap += fe[j] * vsl[j];
    ap += __shfl_xor(ap, 16);
    ap += __shfl_xor(ap, 32);
    float a = ap + cval;
    a = a > 0.f ? a : 0.01f * a;

    const bf16x8 e0 = pack8(fe), e1 = pack8(fe + 8);
    #pragma unroll
    for (int nt = 0; nt < 4; ++nt) {
      f32x4 c = {0.f, 0.f, 0.f, 0.f};
      c = MFMA(e0, *reinterpret_cast<const bf16x8*>(&WeT[(nt * 16 + t) * 72 + q * 8]), c);
      c = MFMA(e1, *reinterpret_cast<const bf16x8*>(&WeT[(nt * 16 + t) * 72 + 32 + q * 8]), c);
      #pragma unroll
      for (int r = 0; r < 4; ++r) {
        float vv = fmaxf(c[r] + beL[nt], 0.f);
        E[(4 * q + r) * 72 + nt * 16 + t] = f2bf(vv);
      }
    }
    sync_wave();

    bf16x8 af[6];
    #pragma unroll
    for (int kc = 0; kc < 4; ++kc) af[kc] = pack8(hraw + kc * 8);
    af[4] = *reinterpret_cast<const bf16x8*>(&E[t * 72 + q * 8]);
    af[5] = *reinterpret_cast<const bf16x8*>(&E[t * 72 + 32 + q * 8]);

    {
      const int sn = (itn < 4) ? __shfl(si0, 16 * itn + t)
                               : __shfl(si1, 16 * (itn - 4) + t);
      const float* hp = nf + (long)sn * 128 + q * 8;
      #pragma unroll
      for (int kc = 0; kc < 4; ++kc) {
        float4 a0 = *reinterpret_cast<const float4*>(hp + kc * 32);
        float4 a1 = *reinterpret_cast<const float4*>(hp + kc * 32 + 4);
        hraw[kc * 8 + 0] = a0.x; hraw[kc * 8 + 1] = a0.y; hraw[kc * 8 + 2] = a0.z; hraw[kc * 8 + 3] = a0.w;
        hraw[kc * 8 + 4] = a1.x; hraw[kc * 8 + 5] = a1.y; hraw[kc * 8 + 6] = a1.z; hraw[kc * 8 + 7] = a1.w;
      }
    }

    f32x4 accM[4];
    #pragma unroll
    for (int nt = 0; nt < 4; ++nt) {
      f32x4 c = {0.f, 0.f, 0.f, 0.f};
      #pragma unroll
      for (int kc = 0; kc < 6; ++kc)
        c = MFMA(af[kc], *reinterpret_cast<const bf16x8*>(&WoT[(nt * 16 + t) * 200 + kc * 32 + q * 8]), c);
      #pragma unroll
      for (int r = 0; r < 4; ++r) c[r] = fmaxf(c[r] + boL[nt], 0.f);
      accM[nt] = c;
    }
    sync_wave();

    float zz = a;
    #pragma unroll
    for (int k = 2; k <= 16; k <<= 1) {
      #pragma unroll
      for (int j = k >> 1; j > 0; j >>= 1) {
        float o = __shfl_xor(zz, j);
        const bool upper = (t & j) != 0;
        const bool desc = (t & k) == 0;
        zz = (upper != desc) ? fmaxf(zz, o) : fminf(zz, o);
      }
    }
    float cs = zz;
    #pragma unroll
    for (int off = 1; off < 16; off <<= 1) {
      float o = __shfl_up(cs, off, 16);
      cs += (t >= off) ? o : 0.f;
    }
    const bool gt = 1.f + (float)(t + 1) * zz > cs;
    float kf = gt ? (float)(t + 1) : 0.f;
    float sv = gt ? zz : 0.f;
    #pragma unroll
    for (int m = 1; m < 16; m <<= 1) {
      kf = fmaxf(kf, __shfl_xor(kf, m));
      sv += __shfl_xor(sv, m);
    }
    const float tau = (sv - 1.f) / kf;
    const float alpha = fmaxf(a - tau, 0.f);

    float al[4];
    #pragma unroll
    for (int r = 0; r < 4; ++r) al[r] = __shfl(alpha, 4 * q + r);
    float p[4];
    #pragma unroll
    for (int nt = 0; nt < 4; ++nt) {
      p[nt] = al[0] * accM[nt][0] + al[1] * accM[nt][1] +
              al[2] * accM[nt][2] + al[3] * accM[nt][3];
      p[nt] += __shfl_xor(p[nt], 16);
      p[nt] += __shfl_xor(p[nt], 32);
    }
    const float pown = (q == 0) ? p[0] : (q == 1) ? p[1] : (q == 2) ? p[2] : p[3];
    hn_out[(long)n * 64 + lane] = pown;
  }
}

// ---------- Fallback out kernel (reads nf, no workspace) ----------
extern "C" __global__ void __launch_bounds__(256, 3)
gteast_out_fb(const float* __restrict__ nf, const float* __restrict__ Wn,
              const float* __restrict__ bn, float* __restrict__ out) {
  __shared__ unsigned short WnT[64 * 200];
  const int tid = threadIdx.x;
  for (int i = tid; i < 192 * 64; i += 256) {
    int k = i >> 6, nn = i & 63;
    WnT[nn * 200 + k] = f2bf(Wn[i]);
  }
  __syncthreads();

  const int lane = tid & 63, w = tid >> 6, q = lane >> 4, t = lane & 15;
  const int tile = blockIdx.x * 4 + w;
  if (tile >= ND / 16) return;
  const int r0 = tile * 16;

  float bnL[4];
  #pragma unroll
  for (int nt = 0; nt < 4; ++nt) bnL[nt] = bn[nt * 16 + t];

  float raw[8];
  bf16x8 af[6];
  const float* hp = nf + (long)(r0 + t) * 128 + q * 8;
  #pragma unroll
  for (int kc = 0; kc < 4; ++kc) {
    float4 a0 = *reinterpret_cast<const float4*>(hp + kc * 32);
    float4 a1 = *reinterpret_cast<const float4*>(hp + kc * 32 + 4);
    raw[0] = a0.x; raw[1] = a0.y; raw[2] = a0.z; raw[3] = a0.w;
    raw[4] = a1.x; raw[5] = a1.y; raw[6] = a1.z; raw[7] = a1.w;
    af[kc] = pack8(raw);
  }
  const float* gp = out + (long)(r0 + t) * 64 + q * 8;
  #pragma unroll
  for (int kc = 0; kc < 2; ++kc) {
    float4 a0 = *reinterpret_cast<const float4*>(gp + kc * 32);
    float4 a1 = *reinterpret_cast<const float4*>(gp + kc * 32 + 4);
    raw[0] = a0.x; raw[1] = a0.y; raw[2] = a0.z; raw[3] = a0.w;
    raw[4] = a1.x; raw[5] = a1.y; raw[6] = a1.z; raw[7] = a1.w;
    af[4 + kc] = pack8(raw);
  }

  #pragma unroll
  for (int nt = 0; nt < 4; ++nt) {
    f32x4 c = {0.f, 0.f, 0.f, 0.f};
    #pragma unroll
    for (int kc = 0; kc < 6; ++kc)
      c = MFMA(af[kc], *reinterpret_cast<const bf16x8*>(&WnT[(nt * 16 + t) * 200 + kc * 32 + q * 8]), c);
    #pragma unroll
    for (int r = 0; r < 4; ++r)
      out[(long)(r0 + 4 * q + r) * 64 + nt * 16 + t] = fmaxf(c[r] + bnL[nt], 0.f);
  }
}

extern "C" void kernel_launch(void* const* d_in, const int* in_sizes, int n_in,
                              void* d_out, int out_size, void* d_ws, size_t ws_size,
                              hipStream_t stream) {
  const float* nf = (const float*)d_in[0];
  const float* ef = (const float*)d_in[1];
  const int* si   = (const int*)d_in[2];
  const float* We = (const float*)d_in[3];
  const float* be = (const float*)d_in[4];
  const float* Wa = (const float*)d_in[5];
  const float* ba = (const float*)d_in[6];
  const float* wa = (const float*)d_in[7];
  const float* Wo = (const float*)d_in[8];
  const float* bo = (const float*)d_in[9];
  const float* Wn = (const float*)d_in[10];
  const float* bn = (const float*)d_in[11];
  float* out = (float*)d_out;
  float* vc = (float*)d_ws;  // 65 floats at ws[0]

  const size_t yneed = 512 + (size_t)NS * 64 * 2 + (size_t)ND * 64 * 2;

  gteast_prep<<<1, 256, 0, stream>>>(Wa, ba, wa, vc);
  if (ws_size >= yneed) {
    unsigned short* y = (unsigned short*)((char*)d_ws + 512);
    unsigned short* z = y + (size_t)NS * 64;
    gteast_src<<<1563, 256, 0, stream>>>(nf, Wo, Wn, y, z);
    gteast_edge<<<1563, 256, 0, stream>>>(ef, si, We, be, Wo, bo, vc, y, out);
    gteast_out<<<782, 256, 0, stream>>>(z, Wn, bn, out);
  } else {
    gteast_edge_fb<<<1563, 256, 0, stream>>>(nf, ef, si, We, be, Wo, bo, vc, out);
    gteast_out_fb<<<782, 256, 0, stream>>>(nf, Wn, bn, out);
  }
}

// Round 6
// 367.896 us; speedup vs baseline: 1.7831x; 1.0058x over previous
//
#include <hip/hip_runtime.h>

// GTEAST layer, round 9: vectorized LDS staging + bf16 h_neigh staging +
// ballot sparsemax tail + prep folded into src.
//   y = nf@Wo_up (100000x64 bf16 frag-packed, ws), z = nf@Wn_up (50000x64,
//   ws), both from gteast_src (one nf read). hn = h_neigh bf16 row-major
//   (ws) so gteast_out loads MFMA A-frags directly (no pack8, no fp32
//   round-trip through d_out).
// Weight LDS staging everywhere: k-pairs packed to u32, ds_write_b32
// (halves staging DS ops; reads stay coalesced row-pairs).
// Sparsemax: count-based front (exact incl. ties); tail = 4-stage fmax
// reduce on kf + __ballot/__ffsll + one shfl for sv (cp==kf => same z =>
// same sp, so any valid lane works).
// Lessons kept: NO invariant-frag hoisting / NO operand-swap e-GEMM
// (rounds 4-6 spilled: +170-230MB scratch writes); Elds round-trip retained
// (~84 VGPR, zero spill); LDS 27.9KB => 5 blocks/CU.

#define ND 50000
#define NS 100000

typedef __bf16 bf16x8 __attribute__((ext_vector_type(8)));
typedef float f32x4 __attribute__((ext_vector_type(4)));
typedef unsigned short u16x4 __attribute__((ext_vector_type(4)));

__device__ __forceinline__ void sync_wave() {
  asm volatile("s_waitcnt lgkmcnt(0)" ::: "memory");
}

// fp32 -> bf16 RNE
__device__ __forceinline__ unsigned short f2bf(float x) {
  unsigned u = __float_as_uint(x);
  u += 0x7fffu + ((u >> 16) & 1u);
  return (unsigned short)(u >> 16);
}
__device__ __forceinline__ float bf2f(unsigned short u) {
  return __uint_as_float((unsigned)u << 16);
}
// two fp32 -> packed u32 of 2 bf16 (lo = first)
__device__ __forceinline__ unsigned f2bf2(float lo, float hi) {
  return (unsigned)f2bf(lo) | ((unsigned)f2bf(hi) << 16);
}

union Frag8 { bf16x8 v; unsigned u32[4]; };

// 8 floats -> bf16x8, round-half-up (+0x8000) + v_perm pack
__device__ __forceinline__ bf16x8 pack8(const float* fr) {
  Frag8 f;
  #pragma unroll
  for (int j = 0; j < 4; ++j) {
    unsigned lo = __float_as_uint(fr[2 * j]) + 0x8000u;
    unsigned hi = __float_as_uint(fr[2 * j + 1]) + 0x8000u;
    f.u32[j] = __builtin_amdgcn_perm(hi, lo, 0x07060302);
  }
  return f.v;
}

#define MFMA(a, b, c) __builtin_amdgcn_mfma_f32_16x16x32_bf16((a), (b), (c), 0, 0, 0)

// ---------- K0 (fallback only): v = Wa@wa, c = ba.wa ----------
extern "C" __global__ void gteast_prep(const float* __restrict__ Wa,
                                       const float* __restrict__ ba,
                                       const float* __restrict__ wa,
                                       float* __restrict__ vc) {
  __shared__ float red[260];
  const int tid = threadIdx.x, k = tid >> 2, p = tid & 3;
  float s = 0.f;
  for (int h = 16 * p; h < 16 * p + 16; ++h) s += Wa[k * 64 + h] * wa[h];
  red[tid] = s;
  if (tid < 4) {
    float sc = 0.f;
    for (int h = 16 * tid; h < 16 * tid + 16; ++h) sc += ba[h] * wa[h];
    red[256 + tid] = sc;
  }
  __syncthreads();
  if (p == 0) vc[k] = red[4 * k] + red[4 * k + 1] + red[4 * k + 2] + red[4 * k + 3];
  if (tid == 0) vc[64] = red[256] + red[257] + red[258] + red[259];
}

// ---------- K_y: y = nf@Wo_up (NS rows), z = nf@Wn_up (ND rows); block
// NS/16/4 (=1563) additionally runs the prep reduction. ----------
extern "C" __global__ void __launch_bounds__(256, 3)
gteast_src(const float* __restrict__ nf, const float* __restrict__ Wo,
           const float* __restrict__ Wn,
           const float* __restrict__ Wa, const float* __restrict__ ba,
           const float* __restrict__ wa,
           unsigned short* __restrict__ y, unsigned short* __restrict__ z,
           float* __restrict__ vc) {
  __shared__ unsigned short WuT[64 * 136];   // Wo_up^T[h][k], stride 136
  __shared__ unsigned short WnuT[64 * 136];  // Wn_up^T[h][k]
  __shared__ float red[260];
  const int tid = threadIdx.x;

  if (blockIdx.x == 1563) {  // folded prep
    const int k = tid >> 2, p = tid & 3;
    float s = 0.f;
    for (int h = 16 * p; h < 16 * p + 16; ++h) s += Wa[k * 64 + h] * wa[h];
    red[tid] = s;
    if (tid < 4) {
      float sc = 0.f;
      for (int h = 16 * tid; h < 16 * tid + 16; ++h) sc += ba[h] * wa[h];
      red[256 + tid] = sc;
    }
    __syncthreads();
    if (p == 0) vc[k] = red[4 * k] + red[4 * k + 1] + red[4 * k + 2] + red[4 * k + 3];
    if (tid == 0) vc[64] = red[256] + red[257] + red[258] + red[259];
    return;
  }

  // paired staging: item i -> (n = i&63, k2 = i>>6), rows 2k2, 2k2+1
  for (int i = tid; i < 64 * 64; i += 256) {
    const int n = i & 63, k2 = i >> 6;
    *reinterpret_cast<unsigned*>(&WuT[n * 136 + 2 * k2]) =
        f2bf2(Wo[(2 * k2) * 64 + n], Wo[(2 * k2 + 1) * 64 + n]);
    *reinterpret_cast<unsigned*>(&WnuT[n * 136 + 2 * k2]) =
        f2bf2(Wn[(2 * k2) * 64 + n], Wn[(2 * k2 + 1) * 64 + n]);
  }
  __syncthreads();

  const int lane = tid & 63, w = tid >> 6, q = lane >> 4, t = lane & 15;
  const int tile = blockIdx.x * 4 + w;  // 6250 active
  if (tile >= NS / 16) return;
  const int r0 = tile * 16;

  float raw[8];
  bf16x8 af[4];
  const float* hp = nf + (long)(r0 + t) * 128 + q * 8;
  #pragma unroll
  for (int kc = 0; kc < 4; ++kc) {
    float4 a0 = *reinterpret_cast<const float4*>(hp + kc * 32);
    float4 a1 = *reinterpret_cast<const float4*>(hp + kc * 32 + 4);
    raw[0] = a0.x; raw[1] = a0.y; raw[2] = a0.z; raw[3] = a0.w;
    raw[4] = a1.x; raw[5] = a1.y; raw[6] = a1.z; raw[7] = a1.w;
    af[kc] = pack8(raw);
  }

  f32x4 accY[4];
  #pragma unroll
  for (int nt = 0; nt < 4; ++nt) {
    f32x4 c = {0.f, 0.f, 0.f, 0.f};
    #pragma unroll
    for (int kc = 0; kc < 4; ++kc)
      c = MFMA(af[kc], *reinterpret_cast<const bf16x8*>(&WuT[(nt * 16 + t) * 136 + kc * 32 + q * 8]), c);
    accY[nt] = c;
  }
  #pragma unroll
  for (int r = 0; r < 4; ++r) {
    u16x4 v = {f2bf(accY[0][r]), f2bf(accY[1][r]), f2bf(accY[2][r]), f2bf(accY[3][r])};
    *reinterpret_cast<u16x4*>(y + (long)(r0 + 4 * q + r) * 64 + t * 4) = v;
  }

  if (tile < ND / 16) {  // z for dst rows only
    f32x4 accZ[4];
    #pragma unroll
    for (int nt = 0; nt < 4; ++nt) {
      f32x4 c = {0.f, 0.f, 0.f, 0.f};
      #pragma unroll
      for (int kc = 0; kc < 4; ++kc)
        c = MFMA(af[kc], *reinterpret_cast<const bf16x8*>(&WnuT[(nt * 16 + t) * 136 + kc * 32 + q * 8]), c);
      accZ[nt] = c;
    }
    #pragma unroll
    for (int r = 0; r < 4; ++r) {
      u16x4 v = {f2bf(accZ[0][r]), f2bf(accZ[1][r]), f2bf(accZ[2][r]), f2bf(accZ[3][r])};
      *reinterpret_cast<u16x4*>(z + (long)(r0 + 4 * q + r) * 64 + t * 4) = v;
    }
  }
}

// ---------- K1: fused e_out + attention + m + sparsemax + h_neigh ----------
extern "C" __global__ void __launch_bounds__(256, 3)
gteast_edge(const float* __restrict__ ef, const int* __restrict__ src_idx,
            const float* __restrict__ We, const float* __restrict__ be,
            const float* __restrict__ Wo, const float* __restrict__ bo,
            const float* __restrict__ vc, const unsigned short* __restrict__ y,
            unsigned short* __restrict__ hn) {
  __shared__ unsigned short WeT[64 * 72];      // We^T[n][k]
  __shared__ unsigned short WoLoT[64 * 72];    // Wo^T rows 128..191 (e_out part)
  __shared__ unsigned short Elds[4][16 * 72];  // per-wave e_out tile [m][h]
  __shared__ float vls[68];                    // v[64], c at [64]

  const int tid = threadIdx.x;
  for (int i = tid; i < 64 * 32; i += 256) {
    const int n = i & 63, k2 = i >> 6;
    *reinterpret_cast<unsigned*>(&WeT[n * 72 + 2 * k2]) =
        f2bf2(We[(2 * k2) * 64 + n], We[(2 * k2 + 1) * 64 + n]);
    *reinterpret_cast<unsigned*>(&WoLoT[n * 72 + 2 * k2]) =
        f2bf2(Wo[(128 + 2 * k2) * 64 + n], Wo[(129 + 2 * k2) * 64 + n]);
  }
  if (tid < 65) vls[tid] = vc[tid];
  __syncthreads();

  const int lane = tid & 63, w = tid >> 6;
  const int q = lane >> 4, t = lane & 15;
  const int wid = blockIdx.x * 4 + w;  // 6250 active
  if (wid * 8 >= ND) return;           // after the only __syncthreads

  unsigned short* E = Elds[w];
  const float cval = vls[64];
  float beL[4], boL[4];
  #pragma unroll
  for (int nt = 0; nt < 4; ++nt) { beL[nt] = be[nt * 16 + t]; boL[nt] = bo[nt * 16 + t]; }
  float vsl[16];
  #pragma unroll
  for (int j = 0; j < 8; ++j) { vsl[j] = vls[q * 8 + j]; vsl[8 + j] = vls[32 + q * 8 + j]; }

  const int si0 = src_idx[wid * 128 + lane];
  const int si1 = src_idx[wid * 128 + 64 + lane];

  const long ebase = (long)(wid * 128);

  // --- prologue: prefetch ef(0) and y(0) ---
  float4 efn[4];
  {
    const float* er = ef + (ebase + t) * 64 + q * 8;
    efn[0] = *reinterpret_cast<const float4*>(er);
    efn[1] = *reinterpret_cast<const float4*>(er + 4);
    efn[2] = *reinterpret_cast<const float4*>(er + 32);
    efn[3] = *reinterpret_cast<const float4*>(er + 36);
  }
  u16x4 yv[4];  // yv[r][nt] = y[src(edge 4q+r)][h=nt*16+t]
  #pragma unroll
  for (int r = 0; r < 4; ++r) {
    const int s0 = __shfl(si0, 4 * q + r);
    yv[r] = *reinterpret_cast<const u16x4*>(y + (long)s0 * 64 + t * 4);
  }

  for (int it = 0; it < 8; ++it) {
    const int n = wid * 8 + it;
    const int itn = it < 7 ? it + 1 : 7;

    // --- snapshot current ef, issue next ef loads ---
    float fe[16];
    fe[0] = efn[0].x; fe[1] = efn[0].y; fe[2] = efn[0].z; fe[3] = efn[0].w;
    fe[4] = efn[1].x; fe[5] = efn[1].y; fe[6] = efn[1].z; fe[7] = efn[1].w;
    fe[8] = efn[2].x; fe[9] = efn[2].y; fe[10] = efn[2].z; fe[11] = efn[2].w;
    fe[12] = efn[3].x; fe[13] = efn[3].y; fe[14] = efn[3].z; fe[15] = efn[3].w;
    {
      const float* er = ef + (ebase + itn * 16 + t) * 64 + q * 8;
      efn[0] = *reinterpret_cast<const float4*>(er);
      efn[1] = *reinterpret_cast<const float4*>(er + 4);
      efn[2] = *reinterpret_cast<const float4*>(er + 32);
      efn[3] = *reinterpret_cast<const float4*>(er + 36);
    }

    // --- fp32 attention logit (exact) ---
    float ap = 0.f;
    #pragma unroll
    for (int j = 0; j < 16; ++j) ap += fe[j] * vsl[j];
    ap += __shfl_xor(ap, 16);
    ap += __shfl_xor(ap, 32);
    float a = ap + cval;
    a = a > 0.f ? a : 0.01f * a;  // leaky_relu

    // --- e GEMM: e_out = relu(ef @ We + be) ---
    const bf16x8 e0 = pack8(fe), e1 = pack8(fe + 8);
    #pragma unroll
    for (int nt = 0; nt < 4; ++nt) {
      f32x4 c = {0.f, 0.f, 0.f, 0.f};
      c = MFMA(e0, *reinterpret_cast<const bf16x8*>(&WeT[(nt * 16 + t) * 72 + q * 8]), c);
      c = MFMA(e1, *reinterpret_cast<const bf16x8*>(&WeT[(nt * 16 + t) * 72 + 32 + q * 8]), c);
      #pragma unroll
      for (int r = 0; r < 4; ++r) {
        float vv = fmaxf(c[r] + beL[nt], 0.f);
        E[(4 * q + r) * 72 + nt * 16 + t] = f2bf(vv);
      }
    }
    sync_wave();

    // --- e_out A-frags from E ---
    bf16x8 af4 = *reinterpret_cast<const bf16x8*>(&E[t * 72 + q * 8]);
    bf16x8 af5 = *reinterpret_cast<const bf16x8*>(&E[t * 72 + 32 + q * 8]);

    // --- m GEMM: m = relu(y[src] + e_out @ Wo_lo + bo), C[edge=4q+r][h=nt*16+t] ---
    f32x4 accM[4];
    #pragma unroll
    for (int nt = 0; nt < 4; ++nt) {
      f32x4 c = {0.f, 0.f, 0.f, 0.f};
      c = MFMA(af4, *reinterpret_cast<const bf16x8*>(&WoLoT[(nt * 16 + t) * 72 + q * 8]), c);
      c = MFMA(af5, *reinterpret_cast<const bf16x8*>(&WoLoT[(nt * 16 + t) * 72 + 32 + q * 8]), c);
      #pragma unroll
      for (int r = 0; r < 4; ++r)
        c[r] = fmaxf(c[r] + bf2f(yv[r][nt]) + boL[nt], 0.f);
      accM[nt] = c;
    }
    sync_wave();  // E reads drained before next iteration's writes

    // --- issue next iteration's y gather (yv regs now free) ---
    #pragma unroll
    for (int r = 0; r < 4; ++r) {
      const int idx = 16 * itn + 4 * q + r;
      const int sn = (idx < 64) ? __shfl(si0, idx) : __shfl(si1, idx - 64);
      yv[r] = *reinterpret_cast<const u16x4*>(y + (long)sn * 64 + t * 4);
    }

    // --- sparsemax over 16 logits (count-based, exact incl. ties) ---
    const float zz = a;
    float cp = 0.f, sp = 0.f;  // partials over j in {4q..4q+3}
    #pragma unroll
    for (int r = 0; r < 4; ++r) {
      float zj = __shfl(zz, 4 * q + r, 16);
      const bool ge = (zj >= zz);
      cp += ge ? 1.f : 0.f;
      sp += ge ? zj : 0.f;
    }
    cp += __shfl_xor(cp, 16); sp += __shfl_xor(sp, 16);
    cp += __shfl_xor(cp, 32); sp += __shfl_xor(sp, 32);
    const bool valid = 1.f + cp * zz > sp;
    float kf = valid ? cp : 0.f;
    #pragma unroll
    for (int m = 1; m < 16; m <<= 1) kf = fmaxf(kf, __shfl_xor(kf, m));
    // sv from any valid lane with cp==kf (equal cp => equal z => equal sp)
    const unsigned long long mk = __ballot(valid && (cp == kf));
    const int base = lane & 48;
    const int sl = __ffsll((unsigned long long)(mk >> base)) - 1 + base;
    const float svm = __shfl(sp, sl);
    const float tau = (svm - 1.f) / kf;
    const float alpha = fmaxf(a - tau, 0.f);  // own edge t

    // --- h_neigh = alpha^T . m ---
    float al[4];
    #pragma unroll
    for (int r = 0; r < 4; ++r) al[r] = __shfl(alpha, 4 * q + r);
    float p[4];
    #pragma unroll
    for (int nt = 0; nt < 4; ++nt) {
      p[nt] = al[0] * accM[nt][0] + al[1] * accM[nt][1] +
              al[2] * accM[nt][2] + al[3] * accM[nt][3];
      p[nt] += __shfl_xor(p[nt], 16);
      p[nt] += __shfl_xor(p[nt], 32);
    }
    const float pown = (q == 0) ? p[0] : (q == 1) ? p[1] : (q == 2) ? p[2] : p[3];
    hn[(long)n * 64 + lane] = f2bf(pown);  // bf16 row-major stage
  }
}

// ---------- K2: out = relu(z[dst] + h_neigh @ Wn_lo + bn) ----------
extern "C" __global__ void __launch_bounds__(256, 4)
gteast_out(const unsigned short* __restrict__ z,
           const unsigned short* __restrict__ hn,
           const float* __restrict__ Wn,
           const float* __restrict__ bn, float* __restrict__ out) {
  __shared__ unsigned short WnLoT[64 * 72];  // Wn^T rows 128..191
  const int tid = threadIdx.x;
  for (int i = tid; i < 64 * 32; i += 256) {
    const int n = i & 63, k2 = i >> 6;
    *reinterpret_cast<unsigned*>(&WnLoT[n * 72 + 2 * k2]) =
        f2bf2(Wn[(128 + 2 * k2) * 64 + n], Wn[(129 + 2 * k2) * 64 + n]);
  }
  __syncthreads();

  const int lane = tid & 63, w = tid >> 6, q = lane >> 4, t = lane & 15;
  const int tile = blockIdx.x * 4 + w;  // 3125 active
  if (tile >= ND / 16) return;
  const int r0 = tile * 16;

  float bnL[4];
  #pragma unroll
  for (int nt = 0; nt < 4; ++nt) bnL[nt] = bn[nt * 16 + t];

  // h_neigh A-frags: direct bf16 loads (staged row-major by K1)
  const unsigned short* gp = hn + (long)(r0 + t) * 64 + q * 8;
  const bf16x8 af4 = *reinterpret_cast<const bf16x8*>(gp);
  const bf16x8 af5 = *reinterpret_cast<const bf16x8*>(gp + 32);

  // z gather (frag-packed, one 8B load per row)
  u16x4 zv[4];
  #pragma unroll
  for (int r = 0; r < 4; ++r)
    zv[r] = *reinterpret_cast<const u16x4*>(z + (long)(r0 + 4 * q + r) * 64 + t * 4);

  #pragma unroll
  for (int nt = 0; nt < 4; ++nt) {
    f32x4 c = {0.f, 0.f, 0.f, 0.f};
    c = MFMA(af4, *reinterpret_cast<const bf16x8*>(&WnLoT[(nt * 16 + t) * 72 + q * 8]), c);
    c = MFMA(af5, *reinterpret_cast<const bf16x8*>(&WnLoT[(nt * 16 + t) * 72 + 32 + q * 8]), c);
    #pragma unroll
    for (int r = 0; r < 4; ++r)
      out[(long)(r0 + 4 * q + r) * 64 + nt * 16 + t] =
          fmaxf(c[r] + bf2f(zv[r][nt]) + bnL[nt], 0.f);
  }
}

// ---------- Fallback edge kernel (round-3 structure, no workspace y) ----------
extern "C" __global__ void __launch_bounds__(256, 3)
gteast_edge_fb(const float* __restrict__ nf, const float* __restrict__ ef,
               const int* __restrict__ src_idx,
               const float* __restrict__ We, const float* __restrict__ be,
               const float* __restrict__ Wo, const float* __restrict__ bo,
               const float* __restrict__ vc,
               float* __restrict__ hn_out) {
  __shared__ unsigned short WeT[64 * 72];
  __shared__ unsigned short WoT[64 * 200];
  __shared__ unsigned short Elds[4][16 * 72];
  __shared__ float vls[68];

  const int tid = threadIdx.x;
  for (int i = tid; i < 64 * 64; i += 256) {
    int k = i >> 6, n = i & 63;
    WeT[n * 72 + k] = f2bf(We[i]);
  }
  for (int i = tid; i < 192 * 64; i += 256) {
    int k = i >> 6, n = i & 63;
    WoT[n * 200 + k] = f2bf(Wo[i]);
  }
  if (tid < 65) vls[tid] = vc[tid];
  __syncthreads();

  const int lane = tid & 63, w = tid >> 6;
  const int q = lane >> 4, t = lane & 15;
  const int wid = blockIdx.x * 4 + w;
  if (wid * 8 >= ND) return;

  unsigned short* E = Elds[w];
  const float cval = vls[64];
  float beL[4], boL[4];
  #pragma unroll
  for (int nt = 0; nt < 4; ++nt) { beL[nt] = be[nt * 16 + t]; boL[nt] = bo[nt * 16 + t]; }
  float vsl[16];
  #pragma unroll
  for (int j = 0; j < 8; ++j) { vsl[j] = vls[q * 8 + j]; vsl[8 + j] = vls[32 + q * 8 + j]; }

  const int si0 = src_idx[wid * 128 + lane];
  const int si1 = src_idx[wid * 128 + 64 + lane];
  const long ebase = (long)(wid * 128);

  float4 efn[4];
  {
    const float* er = ef + (ebase + t) * 64 + q * 8;
    efn[0] = *reinterpret_cast<const float4*>(er);
    efn[1] = *reinterpret_cast<const float4*>(er + 4);
    efn[2] = *reinterpret_cast<const float4*>(er + 32);
    efn[3] = *reinterpret_cast<const float4*>(er + 36);
  }
  float hraw[32];
  {
    const int s0 = __shfl(si0, t);
    const float* hp = nf + (long)s0 * 128 + q * 8;
    #pragma unroll
    for (int kc = 0; kc < 4; ++kc) {
      float4 a0 = *reinterpret_cast<const float4*>(hp + kc * 32);
      float4 a1 = *reinterpret_cast<const float4*>(hp + kc * 32 + 4);
      hraw[kc * 8 + 0] = a0.x; hraw[kc * 8 + 1] = a0.y; hraw[kc * 8 + 2] = a0.z; hraw[kc * 8 + 3] = a0.w;
      hraw[kc * 8 + 4] = a1.x; hraw[kc * 8 + 5] = a1.y; hraw[kc * 8 + 6] = a1.z; hraw[kc * 8 + 7] = a1.w;
    }
  }

  for (int it = 0; it < 8; ++it) {
    const int n = wid * 8 + it;
    const int itn = it < 7 ? it + 1 : 7;

    float fe[16];
    fe[0] = efn[0].x; fe[1] = efn[0].y; fe[2] = efn[0].z; fe[3] = efn[0].w;
    fe[4] = efn[1].x; fe[5] = efn[1].y; fe[6] = efn[1].z; fe[7] = efn[1].w;
    fe[8] = efn[2].x; fe[9] = efn[2].y; fe[10] = efn[2].z; fe[11] = efn[2].w;
    fe[12] = efn[3].x; fe[13] = efn[3].y; fe[14] = efn[3].z; fe[15] = efn[3].w;
    {
      const float* er = ef + (ebase + itn * 16 + t) * 64 + q * 8;
      efn[0] = *reinterpret_cast<const float4*>(er);
      efn[1] = *reinterpret_cast<const float4*>(er + 4);
      efn[2] = *reinterpret_cast<const float4*>(er + 32);
      efn[3] = *reinterpret_cast<const float4*>(er + 36);
    }

    float ap = 0.f;
    #pragma unroll
    for (int j = 0; j < 16; ++j) ap += fe[j] * vsl[j];
    ap += __shfl_xor(ap, 16);
    ap += __shfl_xor(ap, 32);
    float a = ap + cval;
    a = a > 0.f ? a : 0.01f * a;

    const bf16x8 e0 = pack8(fe), e1 = pack8(fe + 8);
    #pragma unroll
    for (int nt = 0; nt < 4; ++nt) {
      f32x4 c = {0.f, 0.f, 0.f, 0.f};
      c = MFMA(e0, *reinterpret_cast<const bf16x8*>(&WeT[(nt * 16 + t) * 72 + q * 8]), c);
      c = MFMA(e1, *reinterpret_cast<const bf16x8*>(&WeT[(nt * 16 + t) * 72 + 32 + q * 8]), c);
      #pragma unroll
      for (int r = 0; r < 4; ++r) {
        float vv = fmaxf(c[r] + beL[nt], 0.f);
        E[(4 * q + r) * 72 + nt * 16 + t] = f2bf(vv);
      }
    }
    sync_wave();

    bf16x8 af[6];
    #pragma unroll
    for (int kc = 0; kc < 4; ++kc) af[kc] = pack8(hraw + kc * 8);
    af[4] = *reinterpret_cast<const bf16x8*>(&E[t * 72 + q * 8]);
    af[5] = *reinterpret_cast<const bf16x8*>(&E[t * 72 + 32 + q * 8]);

    {
      const int sn = (itn < 4) ? __shfl(si0, 16 * itn + t)
                               : __shfl(si1, 16 * (itn - 4) + t);
      const float* hp = nf + (long)sn * 128 + q * 8;
      #pragma unroll
      for (int kc = 0; kc < 4; ++kc) {
        float4 a0 = *reinterpret_cast<const float4*>(hp + kc * 32);
        float4 a1 = *reinterpret_cast<const float4*>(hp + kc * 32 + 4);
        hraw[kc * 8 + 0] = a0.x; hraw[kc * 8 + 1] = a0.y; hraw[kc * 8 + 2] = a0.z; hraw[kc * 8 + 3] = a0.w;
        hraw[kc * 8 + 4] = a1.x; hraw[kc * 8 + 5] = a1.y; hraw[kc * 8 + 6] = a1.z; hraw[kc * 8 + 7] = a1.w;
      }
    }

    f32x4 accM[4];
    #pragma unroll
    for (int nt = 0; nt < 4; ++nt) {
      f32x4 c = {0.f, 0.f, 0.f, 0.f};
      #pragma unroll
      for (int kc = 0; kc < 6; ++kc)
        c = MFMA(af[kc], *reinterpret_cast<const bf16x8*>(&WoT[(nt * 16 + t) * 200 + kc * 32 + q * 8]), c);
      #pragma unroll
      for (int r = 0; r < 4; ++r) c[r] = fmaxf(c[r] + boL[nt], 0.f);
      accM[nt] = c;
    }
    sync_wave();

    float zz = a;
    #pragma unroll
    for (int k = 2; k <= 16; k <<= 1) {
      #pragma unroll
      for (int j = k >> 1; j > 0; j >>= 1) {
        float o = __shfl_xor(zz, j);
        const bool upper = (t & j) != 0;
        const bool desc = (t & k) == 0;
        zz = (upper != desc) ? fmaxf(zz, o) : fminf(zz, o);
      }
    }
    float cs = zz;
    #pragma unroll
    for (int off = 1; off < 16; off <<= 1) {
      float o = __shfl_up(cs, off, 16);
      cs += (t >= off) ? o : 0.f;
    }
    const bool gt = 1.f + (float)(t + 1) * zz > cs;
    float kf = gt ? (float)(t + 1) : 0.f;
    float sv = gt ? zz : 0.f;
    #pragma unroll
    for (int m = 1; m < 16; m <<= 1) {
      kf = fmaxf(kf, __shfl_xor(kf, m));
      sv += __shfl_xor(sv, m);
    }
    const float tau = (sv - 1.f) / kf;
    const float alpha = fmaxf(a - tau, 0.f);

    float al[4];
    #pragma unroll
    for (int r = 0; r < 4; ++r) al[r] = __shfl(alpha, 4 * q + r);
    float p[4];
    #pragma unroll
    for (int nt = 0; nt < 4; ++nt) {
      p[nt] = al[0] * accM[nt][0] + al[1] * accM[nt][1] +
              al[2] * accM[nt][2] + al[3] * accM[nt][3];
      p[nt] += __shfl_xor(p[nt], 16);
      p[nt] += __shfl_xor(p[nt], 32);
    }
    const float pown = (q == 0) ? p[0] : (q == 1) ? p[1] : (q == 2) ? p[2] : p[3];
    hn_out[(long)n * 64 + lane] = pown;
  }
}

// ---------- Fallback out kernel (reads nf, no workspace) ----------
extern "C" __global__ void __launch_bounds__(256, 3)
gteast_out_fb(const float* __restrict__ nf, const float* __restrict__ Wn,
              const float* __restrict__ bn, float* __restrict__ out) {
  __shared__ unsigned short WnT[64 * 200];
  const int tid = threadIdx.x;
  for (int i = tid; i < 192 * 64; i += 256) {
    int k = i >> 6, nn = i & 63;
    WnT[nn * 200 + k] = f2bf(Wn[i]);
  }
  __syncthreads();

  const int lane = tid & 63, w = tid >> 6, q = lane >> 4, t = lane & 15;
  const int tile = blockIdx.x * 4 + w;
  if (tile >= ND / 16) return;
  const int r0 = tile * 16;

  float bnL[4];
  #pragma unroll
  for (int nt = 0; nt < 4; ++nt) bnL[nt] = bn[nt * 16 + t];

  float raw[8];
  bf16x8 af[6];
  const float* hp = nf + (long)(r0 + t) * 128 + q * 8;
  #pragma unroll
  for (int kc = 0; kc < 4; ++kc) {
    float4 a0 = *reinterpret_cast<const float4*>(hp + kc * 32);
    float4 a1 = *reinterpret_cast<const float4*>(hp + kc * 32 + 4);
    raw[0] = a0.x; raw[1] = a0.y; raw[2] = a0.z; raw[3] = a0.w;
    raw[4] = a1.x; raw[5] = a1.y; raw[6] = a1.z; raw[7] = a1.w;
    af[kc] = pack8(raw);
  }
  const float* gp = out + (long)(r0 + t) * 64 + q * 8;
  #pragma unroll
  for (int kc = 0; kc < 2; ++kc) {
    float4 a0 = *reinterpret_cast<const float4*>(gp + kc * 32);
    float4 a1 = *reinterpret_cast<const float4*>(gp + kc * 32 + 4);
    raw[0] = a0.x; raw[1] = a0.y; raw[2] = a0.z; raw[3] = a0.w;
    raw[4] = a1.x; raw[5] = a1.y; raw[6] = a1.z; raw[7] = a1.w;
    af[4 + kc] = pack8(raw);
  }

  #pragma unroll
  for (int nt = 0; nt < 4; ++nt) {
    f32x4 c = {0.f, 0.f, 0.f, 0.f};
    #pragma unroll
    for (int kc = 0; kc < 6; ++kc)
      c = MFMA(af[kc], *reinterpret_cast<const bf16x8*>(&WnT[(nt * 16 + t) * 200 + kc * 32 + q * 8]), c);
    #pragma unroll
    for (int r = 0; r < 4; ++r)
      out[(long)(r0 + 4 * q + r) * 64 + nt * 16 + t] = fmaxf(c[r] + bnL[nt], 0.f);
  }
}

extern "C" void kernel_launch(void* const* d_in, const int* in_sizes, int n_in,
                              void* d_out, int out_size, void* d_ws, size_t ws_size,
                              hipStream_t stream) {
  const float* nf = (const float*)d_in[0];
  const float* ef = (const float*)d_in[1];
  const int* si   = (const int*)d_in[2];
  const float* We = (const float*)d_in[3];
  const float* be = (const float*)d_in[4];
  const float* Wa = (const float*)d_in[5];
  const float* ba = (const float*)d_in[6];
  const float* wa = (const float*)d_in[7];
  const float* Wo = (const float*)d_in[8];
  const float* bo = (const float*)d_in[9];
  const float* Wn = (const float*)d_in[10];
  const float* bn = (const float*)d_in[11];
  float* out = (float*)d_out;
  float* vc = (float*)d_ws;  // 65 floats at ws[0]

  const size_t yneed = 512 + (size_t)NS * 64 * 2 + (size_t)ND * 64 * 2 * 2;

  if (ws_size >= yneed) {
    unsigned short* y = (unsigned short*)((char*)d_ws + 512);
    unsigned short* z = y + (size_t)NS * 64;
    unsigned short* hn = z + (size_t)ND * 64;
    gteast_src<<<1564, 256, 0, stream>>>(nf, Wo, Wn, Wa, ba, wa, y, z, vc);
    gteast_edge<<<1563, 256, 0, stream>>>(ef, si, We, be, Wo, bo, vc, y, hn);
    gteast_out<<<782, 256, 0, stream>>>(z, hn, Wn, bn, out);
  } else {
    gteast_prep<<<1, 256, 0, stream>>>(Wa, ba, wa, vc);
    gteast_edge_fb<<<1563, 256, 0, stream>>>(nf, ef, si, We, be, Wo, bo, vc, out);
    gteast_out_fb<<<782, 256, 0, stream>>>(nf, Wn, bn, out);
  }
}